// Round 1
// baseline (1284.606 us; speedup 1.0000x reference)
//
#include <hip/hip_runtime.h>

// AttentionWindow: out = repr + relu(softmax_masked((repr@W)@repr^T) @ repr)
// BATCH=8, SEQ=2048, HIDDEN=1024, window half-width 64 (|i-j|>64 masked).
// bf16 data path: MFMA (16x16x32 bf16) fused kernel + one-time W-transpose
// into workspace. fp32 data path: previous proven VALU kernel (unchanged).

#define SEQL 2048
#define HID  1024
#define NB   8
#define QT   32     // queries per block
#define KT   160    // candidate keys: [q0-64, q0+95]
#define DCO  128    // d-chunk for Qc GEMM (old kernel)
#define EC   32     // e-chunk staged per inner GEMM step (old kernel)
#define DS   32     // d-slice width (old kernel)
#define RP   36
#define WP   132
#define QP   132
#define KP   36
#define SP   161

#define RS_OFF  0
#define WS_OFF  1152
#define KS_OFF  0
#define QCS_OFF 5760
#define SC_OFF  5760
#define SMEM_F  10912

__device__ __forceinline__ float bfu(unsigned int lo16) {
  union { unsigned int i; float f; } v; v.i = lo16 << 16; return v.f;
}
__device__ __forceinline__ unsigned short f2bf(float f) {
  union { float f; unsigned int i; } v; v.f = f;
  unsigned int r = v.i + 0x7FFFu + ((v.i >> 16) & 1u);   // RNE
  return (unsigned short)(r >> 16);
}

// Uniform dtype sniff (thread-invariant) — unchanged from proven kernel.
__device__ bool data_is_bf16(const unsigned short* u) {
  int cnt = 0;
  for (int i = 0; i < 256; i++) {
    int e = (u[i] >> 7) & 0xFF;
    if (e >= 107 && e <= 131) cnt++;
  }
  return cnt >= 230;
}

template<bool BF16>
__device__ __forceinline__ float4 ld4(const void* p, size_t idx) {
  if (BF16) {
    uint2 u = *(const uint2*)((const unsigned short*)p + idx);
    float4 r;
    r.x = bfu(u.x & 0xFFFFu); r.y = bfu(u.x >> 16);
    r.z = bfu(u.y & 0xFFFFu); r.w = bfu(u.y >> 16);
    return r;
  } else {
    return *(const float4*)((const float*)p + idx);
  }
}

template<bool BF16>
__device__ __forceinline__ void st4(void* p, size_t idx, float4 v) {
  if (BF16) {
    ushort4 o;
    o.x = f2bf(v.x); o.y = f2bf(v.y); o.z = f2bf(v.z); o.w = f2bf(v.w);
    *(ushort4*)((unsigned short*)p + idx) = o;
  } else {
    *(float4*)((float*)p + idx) = v;
  }
}

__device__ __forceinline__ void fma4(float4& q, float a, const float4& w) {
  q.x += a * w.x; q.y += a * w.y; q.z += a * w.z; q.w += a * w.w;
}

// ---------------------------------------------------------------------------
// OLD proven VALU kernel (fp32 path + bf16 fallback when no workspace)
// ---------------------------------------------------------------------------
template<bool BF16>
__global__ void __launch_bounds__(256) attn_fused(
    const void* __restrict__ reprv, const void* __restrict__ Wv,
    void* __restrict__ outv) {
  if (data_is_bf16((const unsigned short*)reprv) != BF16) return;

  __shared__ float smem[SMEM_F];
  const int tid = threadIdx.x;
  const int b = blockIdx.y;
  const int q0 = blockIdx.x * QT;
  const size_t baseR = (size_t)b * SEQL * HID;

  const int tx = tid & 31, ty = tid >> 5;

  float acc[4][5];
#pragma unroll
  for (int i = 0; i < 4; i++)
#pragma unroll
    for (int j = 0; j < 5; j++) acc[i][j] = 0.f;

  for (int d0 = 0; d0 < HID; d0 += DCO) {
    float4 qc[4];
#pragma unroll
    for (int i = 0; i < 4; i++) qc[i] = make_float4(0.f, 0.f, 0.f, 0.f);

    for (int e0 = 0; e0 < HID; e0 += EC) {
      {
        int row = tid >> 3, cg = tid & 7;
        float4 v = ld4<BF16>(reprv, baseR + (size_t)(q0 + row) * HID + e0 + 4 * cg);
        *(float4*)&smem[RS_OFF + row * RP + 4 * cg] = v;
      }
#pragma unroll
      for (int i2 = 0; i2 < 4; i2++) {
        int f = i2 * 256 + tid;
        int row = f >> 5, cg = f & 31;
        float4 v = ld4<BF16>(Wv, (size_t)(e0 + row) * HID + d0 + 4 * cg);
        *(float4*)&smem[WS_OFF + row * WP + 4 * cg] = v;
      }
      __syncthreads();
#pragma unroll
      for (int ee = 0; ee < EC; ee += 4) {
        float4 rv[4];
#pragma unroll
        for (int i = 0; i < 4; i++)
          rv[i] = *(const float4*)&smem[RS_OFF + (ty + 8 * i) * RP + ee];
        {
          float4 wv = *(const float4*)&smem[WS_OFF + (ee + 0) * WP + 4 * tx];
          fma4(qc[0], rv[0].x, wv); fma4(qc[1], rv[1].x, wv);
          fma4(qc[2], rv[2].x, wv); fma4(qc[3], rv[3].x, wv);
        }
        {
          float4 wv = *(const float4*)&smem[WS_OFF + (ee + 1) * WP + 4 * tx];
          fma4(qc[0], rv[0].y, wv); fma4(qc[1], rv[1].y, wv);
          fma4(qc[2], rv[2].y, wv); fma4(qc[3], rv[3].y, wv);
        }
        {
          float4 wv = *(const float4*)&smem[WS_OFF + (ee + 2) * WP + 4 * tx];
          fma4(qc[0], rv[0].z, wv); fma4(qc[1], rv[1].z, wv);
          fma4(qc[2], rv[2].z, wv); fma4(qc[3], rv[3].z, wv);
        }
        {
          float4 wv = *(const float4*)&smem[WS_OFF + (ee + 3) * WP + 4 * tx];
          fma4(qc[0], rv[0].w, wv); fma4(qc[1], rv[1].w, wv);
          fma4(qc[2], rv[2].w, wv); fma4(qc[3], rv[3].w, wv);
        }
      }
      __syncthreads();
    }

#pragma unroll
    for (int i = 0; i < 4; i++)
      *(float4*)&smem[QCS_OFF + (ty + 8 * i) * QP + 4 * tx] = qc[i];

    for (int s = 0; s < DCO; s += DS) {
#pragma unroll
      for (int i2 = 0; i2 < 5; i2++) {
        int f = i2 * 256 + tid;
        int row = f >> 3, cg = f & 7;
        int kk = q0 - 64 + row;
        kk = kk < 0 ? 0 : (kk > SEQL - 1 ? SEQL - 1 : kk);
        float4 v = ld4<BF16>(reprv, baseR + (size_t)kk * HID + d0 + s + 4 * cg);
        *(float4*)&smem[KS_OFF + row * KP + 4 * cg] = v;
      }
      __syncthreads();
#pragma unroll
      for (int dd = 0; dd < DS; dd += 4) {
        float4 qv[4];
#pragma unroll
        for (int i = 0; i < 4; i++)
          qv[i] = *(const float4*)&smem[QCS_OFF + (ty + 8 * i) * QP + s + dd];
#pragma unroll
        for (int j = 0; j < 5; j++) {
          float4 kv = *(const float4*)&smem[KS_OFF + (tx + 32 * j) * KP + dd];
#pragma unroll
          for (int i = 0; i < 4; i++)
            acc[i][j] += qv[i].x * kv.x + qv[i].y * kv.y + qv[i].z * kv.z + qv[i].w * kv.w;
        }
      }
      __syncthreads();
    }
  }

#pragma unroll
  for (int i = 0; i < 4; i++)
#pragma unroll
    for (int j = 0; j < 5; j++)
      smem[SC_OFF + (ty + 8 * i) * SP + tx + 32 * j] = acc[i][j];
  __syncthreads();

  {
    const int row = tid >> 3, l8 = tid & 7;
    int clo = row;          { int t = 64 - q0;            if (t > clo) clo = t; }
    int chi = row + 128;    { int t = SEQL - 1 + 64 - q0; if (t < chi) chi = t; }
    float m = -1e30f;
    for (int c = l8; c < KT; c += 8)
      if (c >= clo && c <= chi) m = fmaxf(m, smem[SC_OFF + row * SP + c]);
    m = fmaxf(m, __shfl_xor(m, 1));
    m = fmaxf(m, __shfl_xor(m, 2));
    m = fmaxf(m, __shfl_xor(m, 4));
    float ssum = 0.f;
    for (int c = l8; c < KT; c += 8) {
      float e = (c >= clo && c <= chi) ? __expf(smem[SC_OFF + row * SP + c] - m) : 0.f;
      smem[SC_OFF + row * SP + c] = e;
      ssum += e;
    }
    ssum += __shfl_xor(ssum, 1);
    ssum += __shfl_xor(ssum, 2);
    ssum += __shfl_xor(ssum, 4);
    float rinv = 1.f / ssum;
    for (int c = l8; c < KT; c += 8) smem[SC_OFF + row * SP + c] *= rinv;
  }
  __syncthreads();

  const int rr = tid >> 3, dq = tid & 7;
  for (int d0 = 0; d0 < HID; d0 += DS) {
#pragma unroll
    for (int i2 = 0; i2 < 5; i2++) {
      int f = i2 * 256 + tid;
      int row = f >> 3, cg = f & 7;
      int kk = q0 - 64 + row;
      kk = kk < 0 ? 0 : (kk > SEQL - 1 ? SEQL - 1 : kk);
      float4 v = ld4<BF16>(reprv, baseR + (size_t)kk * HID + d0 + 4 * cg);
      *(float4*)&smem[KS_OFF + row * KP + 4 * cg] = v;
    }
    __syncthreads();
    float4 o = make_float4(0.f, 0.f, 0.f, 0.f);
#pragma unroll 4
    for (int c = 0; c < KT; c++) {
      float4 kv = *(const float4*)&smem[KS_OFF + c * KP + 4 * dq];
      float p = smem[SC_OFF + rr * SP + c];
      o.x += p * kv.x; o.y += p * kv.y; o.z += p * kv.z; o.w += p * kv.w;
    }
    size_t goff = baseR + (size_t)(q0 + rr) * HID + d0 + 4 * dq;
    float4 rv = ld4<BF16>(reprv, goff);
    float4 ov;
    ov.x = rv.x + fmaxf(o.x, 0.f);
    ov.y = rv.y + fmaxf(o.y, 0.f);
    ov.z = rv.z + fmaxf(o.z, 0.f);
    ov.w = rv.w + fmaxf(o.w, 0.f);
    st4<BF16>(outv, goff, ov);
    __syncthreads();
  }
}

// ---------------------------------------------------------------------------
// NEW bf16 MFMA path
// ---------------------------------------------------------------------------
typedef float f32x4 __attribute__((ext_vector_type(4)));
typedef short bf16x8 __attribute__((ext_vector_type(8)));

#define MF(a_, b_, c_) __builtin_amdgcn_mfma_f32_16x16x32_bf16((a_), (b_), (c_), 0, 0, 0)

// W-transpose: Wt[e][d] = W[d][e], bf16, into workspace. Only runs on bf16 data.
__global__ void __launch_bounds__(256) tposeW(
    const unsigned short* __restrict__ reprB,
    const unsigned short* __restrict__ WB,
    unsigned short* __restrict__ WtB) {
  if (!data_is_bf16(reprB)) return;
  __shared__ alignas(16) unsigned short tl[64 * 72];
  const int t = threadIdx.x;
  const int d0 = (blockIdx.x & 15) * 64, e0 = (blockIdx.x >> 4) * 64;
#pragma unroll
  for (int i = 0; i < 2; i++) {
    int slot = i * 256 + t, row = slot >> 3, c8 = slot & 7;
    *(uint4*)(tl + row * 72 + 8 * c8) =
        *(const uint4*)(WB + (size_t)(d0 + row) * 1024 + e0 + 8 * c8);
  }
  __syncthreads();
#pragma unroll
  for (int i = 0; i < 2; i++) {
    int slot = i * 256 + t, er = slot >> 3, c8 = slot & 7;
    unsigned short v[8];
#pragma unroll
    for (int j = 0; j < 8; j++) v[j] = tl[(8 * c8 + j) * 72 + er];
    *(uint4*)(WtB + (size_t)(e0 + er) * 1024 + d0 + 8 * c8) = *(const uint4*)v;
  }
}

// LDS layout for attn_mfma (offsets in ushorts unless noted):
//  Phase A:  WTS [128][72] @0          (Wt e-slice x d-step 64, single buf)
//            RQS [32][72]  @9216       (R q-tile d-slice)
//            RK  [160][40] @11520      (repr key-tile, 32-wide e-slice)
//            QHI [32][136] @17920      (Q chunk, hi bf16)
//            QLO [32][136] @22272      (Q chunk, lo bf16)   -> 53248 B
//  Phase B:  Sls f32 [32][172] @byte 0 (scores; aliases WTS/RQS, disjoint from RK/QHI)
//            PBF [32][168] @ushort 11008  (probabilities bf16)
//            VT  [64][168] @ushort 16384  (transposed V d-chunk) -> 54272 B
#define WTS_O 0
#define RQS_O 9216
#define RK_O  11520
#define QHI_O 17920
#define QLO_O 22272
#define PBF_O 11008
#define VT_O  16384
#define SMEMU 27136   // ushorts = 54272 B  (2 blocks/CU)

__global__ void __launch_bounds__(256, 2) attn_mfma(
    const unsigned short* __restrict__ reprB,
    const unsigned short* __restrict__ WtB,
    unsigned short* __restrict__ outB) {
  if (!data_is_bf16(reprB)) return;

  __shared__ alignas(16) unsigned short sm[SMEMU];
  float* smf = (float*)sm;

  const int tid = threadIdx.x;
  const int w = tid >> 6, l = tid & 63, lr = l & 15, lg = l >> 4;
  const int b = blockIdx.y, q0 = blockIdx.x * 32;
  const size_t baseR = (size_t)b * 2048 * 1024;
  const int qt = w >> 1;           // q-tile this wave owns for S/PV
  const int ktb = (w & 1) * 5;     // S key-tile base (5 tiles per wave)

  f32x4 acc_s[5];
#pragma unroll
  for (int j = 0; j < 5; j++) acc_s[j] = (f32x4){0.f, 0.f, 0.f, 0.f};

  // ---------------- Phase A: Q = R@Wt (per 128-e chunk) + S accumulate ------
  for (int ec = 0; ec < 8; ec++) {
    const int e0 = ec * 128;
    f32x4 acc_q[2][2];
#pragma unroll
    for (int i = 0; i < 2; i++)
#pragma unroll
      for (int j = 0; j < 2; j++) acc_q[i][j] = (f32x4){0.f, 0.f, 0.f, 0.f};

    // d-loop: 16 stages of d-step 64 (2 MFMA K-steps per stage)
    for (int s = 0; s < 16; s++) {
      const int d0 = s * 64;
      uint4 wtr[4], rqr;
#pragma unroll
      for (int i = 0; i < 4; i++) {
        int slot = i * 256 + tid, row = slot >> 3, c8 = slot & 7;
        wtr[i] = *(const uint4*)(WtB + (size_t)(e0 + row) * 1024 + d0 + 8 * c8);
      }
      {
        int row = tid >> 3, c8 = tid & 7;
        rqr = *(const uint4*)(reprB + baseR + (size_t)(q0 + row) * 1024 + d0 + 8 * c8);
      }
      __syncthreads();   // previous stage's reads complete
#pragma unroll
      for (int i = 0; i < 4; i++) {
        int slot = i * 256 + tid, row = slot >> 3, c8 = slot & 7;
        *(uint4*)(sm + WTS_O + row * 72 + 8 * c8) = wtr[i];
      }
      {
        int row = tid >> 3, c8 = tid & 7;
        *(uint4*)(sm + RQS_O + row * 72 + 8 * c8) = rqr;
      }
      __syncthreads();   // writes visible
#pragma unroll
      for (int h = 0; h < 2; h++) {
        bf16x8 a0 = *(const bf16x8*)(sm + RQS_O + (lr) * 72 + 32 * h + 8 * lg);
        bf16x8 a1 = *(const bf16x8*)(sm + RQS_O + (16 + lr) * 72 + 32 * h + 8 * lg);
        bf16x8 b0 = *(const bf16x8*)(sm + WTS_O + (32 * w + lr) * 72 + 32 * h + 8 * lg);
        bf16x8 b1 = *(const bf16x8*)(sm + WTS_O + (32 * w + 16 + lr) * 72 + 32 * h + 8 * lg);
        acc_q[0][0] = MF(a0, b0, acc_q[0][0]);
        acc_q[0][1] = MF(a0, b1, acc_q[0][1]);
        acc_q[1][0] = MF(a1, b0, acc_q[1][0]);
        acc_q[1][1] = MF(a1, b1, acc_q[1][1]);
      }
    }

    // A2: accumulators -> QHI/QLO (hi/lo bf16 split for precision)
#pragma unroll
    for (int qq = 0; qq < 2; qq++)
#pragma unroll
      for (int et = 0; et < 2; et++)
#pragma unroll
        for (int r = 0; r < 4; r++) {
          int row = 16 * qq + 4 * lg + r;
          int col = 32 * w + 16 * et + lr;
          float v = acc_q[qq][et][r];
          unsigned short hi = f2bf(v);
          sm[QHI_O + row * 136 + col] = hi;
          sm[QLO_O + row * 136 + col] = f2bf(v - bfu(hi));
        }

    // A3: S += Qchunk @ Rk^T over this e-chunk (4 e-slices of 32)
    for (int es = 0; es < 4; es++) {
      uint4 rkr[3];
#pragma unroll
      for (int i = 0; i < 3; i++) {
        int slot = i * 256 + tid;
        if (slot < 640) {
          int row = slot >> 2, c8 = slot & 3;
          int kk = q0 - 64 + row;
          kk = kk < 0 ? 0 : (kk > 2047 ? 2047 : kk);
          rkr[i] = *(const uint4*)(reprB + baseR + (size_t)kk * 1024 + e0 + 32 * es + 8 * c8);
        }
      }
      __syncthreads();   // QHI writes (es==0) + previous RK reads done
#pragma unroll
      for (int i = 0; i < 3; i++) {
        int slot = i * 256 + tid;
        if (slot < 640) {
          int row = slot >> 2, c8 = slot & 3;
          *(uint4*)(sm + RK_O + row * 40 + 8 * c8) = rkr[i];
        }
      }
      __syncthreads();
      bf16x8 qh = *(const bf16x8*)(sm + QHI_O + (16 * qt + lr) * 136 + 32 * es + 8 * lg);
      bf16x8 ql = *(const bf16x8*)(sm + QLO_O + (16 * qt + lr) * 136 + 32 * es + 8 * lg);
#pragma unroll
      for (int j = 0; j < 5; j++) {
        bf16x8 kv = *(const bf16x8*)(sm + RK_O + (16 * (ktb + j) + lr) * 40 + 8 * lg);
        acc_s[j] = MF(qh, kv, acc_s[j]);
        acc_s[j] = MF(ql, kv, acc_s[j]);
      }
    }
  }

  __syncthreads();
  // scores -> Sls (f32, pitch 172); Sls aliases WTS/RQS (dead), disjoint from RK/QHI
#pragma unroll
  for (int j = 0; j < 5; j++)
#pragma unroll
    for (int r = 0; r < 4; r++) {
      int row = 16 * qt + 4 * lg + r;
      int col = 16 * (ktb + j) + lr;
      smf[row * 172 + col] = acc_s[j][r];
    }
  __syncthreads();

  // ---------------- masked softmax: 8 lanes per query row (proven code) -----
  {
    const int row = tid >> 3, l8 = tid & 7;
    int clo = row;          { int t2 = 64 - q0;            if (t2 > clo) clo = t2; }
    int chi = row + 128;    { int t2 = 2047 + 64 - q0;     if (t2 < chi) chi = t2; }
    float m = -1e30f;
    for (int c = l8; c < 160; c += 8)
      if (c >= clo && c <= chi) m = fmaxf(m, smf[row * 172 + c]);
    m = fmaxf(m, __shfl_xor(m, 1));
    m = fmaxf(m, __shfl_xor(m, 2));
    m = fmaxf(m, __shfl_xor(m, 4));
    float ssum = 0.f;
    for (int c = l8; c < 160; c += 8) {
      float e = (c >= clo && c <= chi) ? __expf(smf[row * 172 + c] - m) : 0.f;
      smf[row * 172 + c] = e;
      ssum += e;
    }
    ssum += __shfl_xor(ssum, 1);
    ssum += __shfl_xor(ssum, 2);
    ssum += __shfl_xor(ssum, 4);
    float rinv = 1.f / ssum;
    for (int c = l8; c < 160; c += 8)
      sm[PBF_O + row * 168 + c] = f2bf(smf[row * 172 + c] * rinv);
  }
  __syncthreads();

  // ---------------- Phase B: ra = P @ V (MFMA), out = repr + relu(ra) -------
  const int dtl = (w & 1) * 2;
  bf16x8 pa[5];
#pragma unroll
  for (int ks = 0; ks < 5; ks++)
    pa[ks] = *(const bf16x8*)(sm + PBF_O + (16 * qt + lr) * 168 + 32 * ks + 8 * lg);

  for (int dc = 0; dc < 16; dc++) {
    const int d0 = dc * 64;
    uint4 vr[5];
#pragma unroll
    for (int i = 0; i < 5; i++) {
      int slot = i * 256 + tid;            // exactly 1280 slots
      int k = slot >> 3, g = slot & 7;
      int kk = q0 - 64 + k;
      kk = kk < 0 ? 0 : (kk > 2047 ? 2047 : kk);
      vr[i] = *(const uint4*)(reprB + baseR + (size_t)kk * 1024 + d0 + 8 * g);
    }
    __syncthreads();   // previous chunk's VT reads done
#pragma unroll
    for (int i = 0; i < 5; i++) {
      int slot = i * 256 + tid;
      int k = slot >> 3, g = slot & 7;
      const unsigned short* pv = (const unsigned short*)&vr[i];
#pragma unroll
      for (int j2 = 0; j2 < 8; j2++)
        sm[VT_O + (8 * g + j2) * 168 + k] = pv[j2];   // scatter transpose
    }
    __syncthreads();
    f32x4 ra0 = (f32x4){0.f, 0.f, 0.f, 0.f};
    f32x4 ra1 = (f32x4){0.f, 0.f, 0.f, 0.f};
#pragma unroll
    for (int ks = 0; ks < 5; ks++) {
      bf16x8 v0 = *(const bf16x8*)(sm + VT_O + (16 * dtl + lr) * 168 + 32 * ks + 8 * lg);
      bf16x8 v1 = *(const bf16x8*)(sm + VT_O + (16 * (dtl + 1) + lr) * 168 + 32 * ks + 8 * lg);
      ra0 = MF(pa[ks], v0, ra0);
      ra1 = MF(pa[ks], v1, ra1);
    }
    // epilogue: residual + relu, bf16 store
#pragma unroll
    for (int r = 0; r < 4; r++) {
      int qg = q0 + 16 * qt + 4 * lg + r;
      size_t base = baseR + (size_t)qg * 1024 + d0;
      int dg0 = 16 * dtl + lr, dg1 = 16 * (dtl + 1) + lr;
      float o0 = bfu(reprB[base + dg0]) + fmaxf(ra0[r], 0.f);
      float o1 = bfu(reprB[base + dg1]) + fmaxf(ra1[r], 0.f);
      outB[base + dg0] = f2bf(o0);
      outB[base + dg1] = f2bf(o1);
    }
  }
}

extern "C" void kernel_launch(void* const* d_in, const int* in_sizes, int n_in,
                              void* d_out, int out_size, void* d_ws, size_t ws_size,
                              hipStream_t stream) {
  const void* repr = d_in[0];
  const void* W    = d_in[1];
  dim3 grid(SEQL / QT, NB);   // (64, 8) = 512 blocks

  const bool use_mfma = (d_ws != nullptr) && (ws_size >= (size_t)2 * 1024 * 1024);
  if (use_mfma) {
    tposeW<<<dim3(256), dim3(256), 0, stream>>>(
        (const unsigned short*)repr, (const unsigned short*)W, (unsigned short*)d_ws);
    attn_mfma<<<grid, dim3(256), 0, stream>>>(
        (const unsigned short*)repr, (const unsigned short*)d_ws, (unsigned short*)d_out);
  } else {
    attn_fused<true><<<grid, dim3(256), 0, stream>>>(repr, W, d_out);
  }
  attn_fused<false><<<grid, dim3(256), 0, stream>>>(repr, W, d_out);
}

// Round 3
// 578.778 us; speedup vs baseline: 2.2195x; 2.2195x over previous
//
#include <hip/hip_runtime.h>

// AttentionWindow: out = repr + relu(softmax_masked((repr@W)@repr^T) @ repr)
// BATCH=8, SEQ=2048, HIDDEN=1024, window half-width 64 (|i-j|>64 masked).
//
// Three data modes, detected per-block by a uniform sniff of repr's bytes:
//   bf16 data  -> attn_mfma      (verified in round 1, unchanged)
//   fp32 data  -> attn_mfma_f32  (bf16 hi/lo split MFMA, ~fp32 accuracy)
//   no workspace fallback -> proven VALU pair.
// tposeW2 pre-transposes W into workspace once per launch:
//   bf16 mode: Wt bf16 @0 (2 MB) ; fp32 mode: WtHi @0 (2MB) + WtLo @2MB.

#define SEQL 2048
#define HID  1024
#define NB   8
#define QT   32
#define KT   160
#define DCO  128
#define EC   32
#define DS   32
#define RP   36
#define WP   132
#define QP   132
#define KP   36
#define SP   161

#define RS_OFF  0
#define WS_OFF  1152
#define KS_OFF  0
#define QCS_OFF 5760
#define SC_OFF  5760
#define SMEM_F  10912

__device__ __forceinline__ float bfu(unsigned int lo16) {
  union { unsigned int i; float f; } v; v.i = lo16 << 16; return v.f;
}
__device__ __forceinline__ unsigned short f2bf(float f) {
  union { float f; unsigned int i; } v; v.f = f;
  unsigned int r = v.i + 0x7FFFu + ((v.i >> 16) & 1u);   // RNE
  return (unsigned short)(r >> 16);
}
__device__ __forceinline__ void hilo(float v, unsigned short& h, unsigned short& l) {
  h = f2bf(v);
  l = f2bf(v - bfu(h));
}

// Uniform dtype sniff (thread-invariant).
__device__ bool data_is_bf16(const unsigned short* u) {
  int cnt = 0;
  for (int i = 0; i < 256; i++) {
    int e = (u[i] >> 7) & 0xFF;
    if (e >= 107 && e <= 131) cnt++;
  }
  return cnt >= 230;
}

template<bool BF16>
__device__ __forceinline__ float4 ld4(const void* p, size_t idx) {
  if (BF16) {
    uint2 u = *(const uint2*)((const unsigned short*)p + idx);
    float4 r;
    r.x = bfu(u.x & 0xFFFFu); r.y = bfu(u.x >> 16);
    r.z = bfu(u.y & 0xFFFFu); r.w = bfu(u.y >> 16);
    return r;
  } else {
    return *(const float4*)((const float*)p + idx);
  }
}

template<bool BF16>
__device__ __forceinline__ void st4(void* p, size_t idx, float4 v) {
  if (BF16) {
    ushort4 o;
    o.x = f2bf(v.x); o.y = f2bf(v.y); o.z = f2bf(v.z); o.w = f2bf(v.w);
    *(ushort4*)((unsigned short*)p + idx) = o;
  } else {
    *(float4*)((float*)p + idx) = v;
  }
}

__device__ __forceinline__ void fma4(float4& q, float a, const float4& w) {
  q.x += a * w.x; q.y += a * w.y; q.z += a * w.z; q.w += a * w.w;
}

// ---------------------------------------------------------------------------
// OLD proven VALU kernel (fallback when no workspace)
// ---------------------------------------------------------------------------
template<bool BF16>
__global__ void __launch_bounds__(256) attn_fused(
    const void* __restrict__ reprv, const void* __restrict__ Wv,
    void* __restrict__ outv) {
  if (data_is_bf16((const unsigned short*)reprv) != BF16) return;

  __shared__ float smem[SMEM_F];
  const int tid = threadIdx.x;
  const int b = blockIdx.y;
  const int q0 = blockIdx.x * QT;
  const size_t baseR = (size_t)b * SEQL * HID;

  const int tx = tid & 31, ty = tid >> 5;

  float acc[4][5];
#pragma unroll
  for (int i = 0; i < 4; i++)
#pragma unroll
    for (int j = 0; j < 5; j++) acc[i][j] = 0.f;

  for (int d0 = 0; d0 < HID; d0 += DCO) {
    float4 qc[4];
#pragma unroll
    for (int i = 0; i < 4; i++) qc[i] = make_float4(0.f, 0.f, 0.f, 0.f);

    for (int e0 = 0; e0 < HID; e0 += EC) {
      {
        int row = tid >> 3, cg = tid & 7;
        float4 v = ld4<BF16>(reprv, baseR + (size_t)(q0 + row) * HID + e0 + 4 * cg);
        *(float4*)&smem[RS_OFF + row * RP + 4 * cg] = v;
      }
#pragma unroll
      for (int i2 = 0; i2 < 4; i2++) {
        int f = i2 * 256 + tid;
        int row = f >> 5, cg = f & 31;
        float4 v = ld4<BF16>(Wv, (size_t)(e0 + row) * HID + d0 + 4 * cg);
        *(float4*)&smem[WS_OFF + row * WP + 4 * cg] = v;
      }
      __syncthreads();
#pragma unroll
      for (int ee = 0; ee < EC; ee += 4) {
        float4 rv[4];
#pragma unroll
        for (int i = 0; i < 4; i++)
          rv[i] = *(const float4*)&smem[RS_OFF + (ty + 8 * i) * RP + ee];
        {
          float4 wv = *(const float4*)&smem[WS_OFF + (ee + 0) * WP + 4 * tx];
          fma4(qc[0], rv[0].x, wv); fma4(qc[1], rv[1].x, wv);
          fma4(qc[2], rv[2].x, wv); fma4(qc[3], rv[3].x, wv);
        }
        {
          float4 wv = *(const float4*)&smem[WS_OFF + (ee + 1) * WP + 4 * tx];
          fma4(qc[0], rv[0].y, wv); fma4(qc[1], rv[1].y, wv);
          fma4(qc[2], rv[2].y, wv); fma4(qc[3], rv[3].y, wv);
        }
        {
          float4 wv = *(const float4*)&smem[WS_OFF + (ee + 2) * WP + 4 * tx];
          fma4(qc[0], rv[0].z, wv); fma4(qc[1], rv[1].z, wv);
          fma4(qc[2], rv[2].z, wv); fma4(qc[3], rv[3].z, wv);
        }
        {
          float4 wv = *(const float4*)&smem[WS_OFF + (ee + 3) * WP + 4 * tx];
          fma4(qc[0], rv[0].w, wv); fma4(qc[1], rv[1].w, wv);
          fma4(qc[2], rv[2].w, wv); fma4(qc[3], rv[3].w, wv);
        }
      }
      __syncthreads();
    }

#pragma unroll
    for (int i = 0; i < 4; i++)
      *(float4*)&smem[QCS_OFF + (ty + 8 * i) * QP + 4 * tx] = qc[i];

    for (int s = 0; s < DCO; s += DS) {
#pragma unroll
      for (int i2 = 0; i2 < 5; i2++) {
        int f = i2 * 256 + tid;
        int row = f >> 3, cg = f & 7;
        int kk = q0 - 64 + row;
        kk = kk < 0 ? 0 : (kk > SEQL - 1 ? SEQL - 1 : kk);
        float4 v = ld4<BF16>(reprv, baseR + (size_t)kk * HID + d0 + s + 4 * cg);
        *(float4*)&smem[KS_OFF + row * KP + 4 * cg] = v;
      }
      __syncthreads();
#pragma unroll
      for (int dd = 0; dd < DS; dd += 4) {
        float4 qv[4];
#pragma unroll
        for (int i = 0; i < 4; i++)
          qv[i] = *(const float4*)&smem[QCS_OFF + (ty + 8 * i) * QP + s + dd];
#pragma unroll
        for (int j = 0; j < 5; j++) {
          float4 kv = *(const float4*)&smem[KS_OFF + (tx + 32 * j) * KP + dd];
#pragma unroll
          for (int i = 0; i < 4; i++)
            acc[i][j] += qv[i].x * kv.x + qv[i].y * kv.y + qv[i].z * kv.z + qv[i].w * kv.w;
        }
      }
      __syncthreads();
    }
  }

#pragma unroll
  for (int i = 0; i < 4; i++)
#pragma unroll
    for (int j = 0; j < 5; j++)
      smem[SC_OFF + (ty + 8 * i) * SP + tx + 32 * j] = acc[i][j];
  __syncthreads();

  {
    const int row = tid >> 3, l8 = tid & 7;
    int clo = row;          { int t = 64 - q0;            if (t > clo) clo = t; }
    int chi = row + 128;    { int t = SEQL - 1 + 64 - q0; if (t < chi) chi = t; }
    float m = -1e30f;
    for (int c = l8; c < KT; c += 8)
      if (c >= clo && c <= chi) m = fmaxf(m, smem[SC_OFF + row * SP + c]);
    m = fmaxf(m, __shfl_xor(m, 1));
    m = fmaxf(m, __shfl_xor(m, 2));
    m = fmaxf(m, __shfl_xor(m, 4));
    float ssum = 0.f;
    for (int c = l8; c < KT; c += 8) {
      float e = (c >= clo && c <= chi) ? __expf(smem[SC_OFF + row * SP + c] - m) : 0.f;
      smem[SC_OFF + row * SP + c] = e;
      ssum += e;
    }
    ssum += __shfl_xor(ssum, 1);
    ssum += __shfl_xor(ssum, 2);
    ssum += __shfl_xor(ssum, 4);
    float rinv = 1.f / ssum;
    for (int c = l8; c < KT; c += 8) smem[SC_OFF + row * SP + c] *= rinv;
  }
  __syncthreads();

  const int rr = tid >> 3, dq = tid & 7;
  for (int d0 = 0; d0 < HID; d0 += DS) {
#pragma unroll
    for (int i2 = 0; i2 < 5; i2++) {
      int f = i2 * 256 + tid;
      int row = f >> 3, cg = f & 7;
      int kk = q0 - 64 + row;
      kk = kk < 0 ? 0 : (kk > SEQL - 1 ? SEQL - 1 : kk);
      float4 v = ld4<BF16>(reprv, baseR + (size_t)kk * HID + d0 + 4 * cg);
      *(float4*)&smem[KS_OFF + row * KP + 4 * cg] = v;
    }
    __syncthreads();
    float4 o = make_float4(0.f, 0.f, 0.f, 0.f);
#pragma unroll 4
    for (int c = 0; c < KT; c++) {
      float4 kv = *(const float4*)&smem[KS_OFF + c * KP + 4 * dq];
      float p = smem[SC_OFF + rr * SP + c];
      o.x += p * kv.x; o.y += p * kv.y; o.z += p * kv.z; o.w += p * kv.w;
    }
    size_t goff = baseR + (size_t)(q0 + rr) * HID + d0 + 4 * dq;
    float4 rv = ld4<BF16>(reprv, goff);
    float4 ov;
    ov.x = rv.x + fmaxf(o.x, 0.f);
    ov.y = rv.y + fmaxf(o.y, 0.f);
    ov.z = rv.z + fmaxf(o.z, 0.f);
    ov.w = rv.w + fmaxf(o.w, 0.f);
    st4<BF16>(outv, goff, ov);
    __syncthreads();
  }
}

// ---------------------------------------------------------------------------
// MFMA common
// ---------------------------------------------------------------------------
typedef float f32x4 __attribute__((ext_vector_type(4)));
typedef short bf16x8 __attribute__((ext_vector_type(8)));

#define MF(a_, b_, c_) __builtin_amdgcn_mfma_f32_16x16x32_bf16((a_), (b_), (c_), 0, 0, 0)

// W-transpose (dual-mode). bf16 data: Wt bf16 @ws0 (2MB, exact).
// fp32 data: WtHi @ws0 (2MB) + WtLo @ws+2MB (bf16 hi/lo split of W^T).
__global__ void __launch_bounds__(256) tposeW2(
    const void* __restrict__ reprv, const void* __restrict__ Wv,
    void* __restrict__ wsv) {
  const bool isbf = data_is_bf16((const unsigned short*)reprv);
  __shared__ alignas(16) unsigned char twsb[64 * 68 * 4];
  const int t = threadIdx.x;
  const int d0 = (blockIdx.x & 15) * 64, e0 = (blockIdx.x >> 4) * 64;
  if (isbf) {
    unsigned short* tl = (unsigned short*)twsb;
    const unsigned short* WB = (const unsigned short*)Wv;
    unsigned short* WtB = (unsigned short*)wsv;
#pragma unroll
    for (int i = 0; i < 2; i++) {
      int slot = i * 256 + t, row = slot >> 3, c8 = slot & 7;
      *(uint4*)(tl + row * 72 + 8 * c8) =
          *(const uint4*)(WB + (size_t)(d0 + row) * 1024 + e0 + 8 * c8);
    }
    __syncthreads();
#pragma unroll
    for (int i = 0; i < 2; i++) {
      int slot = i * 256 + t, er = slot >> 3, c8 = slot & 7;
      unsigned short v[8];
#pragma unroll
      for (int j = 0; j < 8; j++) v[j] = tl[(8 * c8 + j) * 72 + er];
      *(uint4*)(WtB + (size_t)(e0 + er) * 1024 + d0 + 8 * c8) = *(const uint4*)v;
    }
  } else {
    float* tlf = (float*)twsb;
    const float* WF = (const float*)Wv;
    unsigned short* WtH = (unsigned short*)wsv;
    unsigned short* WtL = WtH + (1u << 20);   // +2 MB
#pragma unroll
    for (int i = 0; i < 4; i++) {
      int slot = i * 256 + t, row = slot >> 4, cf = slot & 15;
      *(float4*)&tlf[row * 68 + 4 * cf] =
          *(const float4*)(WF + (size_t)(d0 + row) * 1024 + e0 + 4 * cf);
    }
    __syncthreads();
#pragma unroll
    for (int i = 0; i < 2; i++) {
      int slot = i * 256 + t, er = slot >> 3, c8 = slot & 7;
      unsigned short vh[8], vl[8];
#pragma unroll
      for (int j = 0; j < 8; j++) {
        float v = tlf[(8 * c8 + j) * 68 + er];
        hilo(v, vh[j], vl[j]);
      }
      *(uint4*)(WtH + (size_t)(e0 + er) * 1024 + d0 + 8 * c8) = *(const uint4*)vh;
      *(uint4*)(WtL + (size_t)(e0 + er) * 1024 + d0 + 8 * c8) = *(const uint4*)vl;
    }
  }
}

// ---------------------------------------------------------------------------
// bf16-data MFMA kernel (round-1 verified, unchanged)
// ---------------------------------------------------------------------------
#define WTS_O 0
#define RQS_O 9216
#define RK_O  11520
#define QHI_O 17920
#define QLO_O 22272
#define PBF_O 11008
#define VT_O  16384
#define SMEMU 27136

__global__ void __launch_bounds__(256, 2) attn_mfma(
    const unsigned short* __restrict__ reprB,
    const unsigned short* __restrict__ WtB,
    unsigned short* __restrict__ outB) {
  if (!data_is_bf16(reprB)) return;

  __shared__ alignas(16) unsigned short sm[SMEMU];
  float* smf = (float*)sm;

  const int tid = threadIdx.x;
  const int w = tid >> 6, l = tid & 63, lr = l & 15, lg = l >> 4;
  const int b = blockIdx.y, q0 = blockIdx.x * 32;
  const size_t baseR = (size_t)b * 2048 * 1024;
  const int qt = w >> 1;
  const int ktb = (w & 1) * 5;

  f32x4 acc_s[5];
#pragma unroll
  for (int j = 0; j < 5; j++) acc_s[j] = (f32x4){0.f, 0.f, 0.f, 0.f};

  for (int ec = 0; ec < 8; ec++) {
    const int e0 = ec * 128;
    f32x4 acc_q[2][2];
#pragma unroll
    for (int i = 0; i < 2; i++)
#pragma unroll
      for (int j = 0; j < 2; j++) acc_q[i][j] = (f32x4){0.f, 0.f, 0.f, 0.f};

    for (int s = 0; s < 16; s++) {
      const int d0 = s * 64;
      uint4 wtr[4], rqr;
#pragma unroll
      for (int i = 0; i < 4; i++) {
        int slot = i * 256 + tid, row = slot >> 3, c8 = slot & 7;
        wtr[i] = *(const uint4*)(WtB + (size_t)(e0 + row) * 1024 + d0 + 8 * c8);
      }
      {
        int row = tid >> 3, c8 = tid & 7;
        rqr = *(const uint4*)(reprB + baseR + (size_t)(q0 + row) * 1024 + d0 + 8 * c8);
      }
      __syncthreads();
#pragma unroll
      for (int i = 0; i < 4; i++) {
        int slot = i * 256 + tid, row = slot >> 3, c8 = slot & 7;
        *(uint4*)(sm + WTS_O + row * 72 + 8 * c8) = wtr[i];
      }
      {
        int row = tid >> 3, c8 = tid & 7;
        *(uint4*)(sm + RQS_O + row * 72 + 8 * c8) = rqr;
      }
      __syncthreads();
#pragma unroll
      for (int h = 0; h < 2; h++) {
        bf16x8 a0 = *(const bf16x8*)(sm + RQS_O + (lr) * 72 + 32 * h + 8 * lg);
        bf16x8 a1 = *(const bf16x8*)(sm + RQS_O + (16 + lr) * 72 + 32 * h + 8 * lg);
        bf16x8 b0 = *(const bf16x8*)(sm + WTS_O + (32 * w + lr) * 72 + 32 * h + 8 * lg);
        bf16x8 b1 = *(const bf16x8*)(sm + WTS_O + (32 * w + 16 + lr) * 72 + 32 * h + 8 * lg);
        acc_q[0][0] = MF(a0, b0, acc_q[0][0]);
        acc_q[0][1] = MF(a0, b1, acc_q[0][1]);
        acc_q[1][0] = MF(a1, b0, acc_q[1][0]);
        acc_q[1][1] = MF(a1, b1, acc_q[1][1]);
      }
    }

#pragma unroll
    for (int qq = 0; qq < 2; qq++)
#pragma unroll
      for (int et = 0; et < 2; et++)
#pragma unroll
        for (int r = 0; r < 4; r++) {
          int row = 16 * qq + 4 * lg + r;
          int col = 32 * w + 16 * et + lr;
          float v = acc_q[qq][et][r];
          unsigned short hi = f2bf(v);
          sm[QHI_O + row * 136 + col] = hi;
          sm[QLO_O + row * 136 + col] = f2bf(v - bfu(hi));
        }

    for (int es = 0; es < 4; es++) {
      uint4 rkr[3];
#pragma unroll
      for (int i = 0; i < 3; i++) {
        int slot = i * 256 + tid;
        if (slot < 640) {
          int row = slot >> 2, c8 = slot & 3;
          int kk = q0 - 64 + row;
          kk = kk < 0 ? 0 : (kk > 2047 ? 2047 : kk);
          rkr[i] = *(const uint4*)(reprB + baseR + (size_t)kk * 1024 + e0 + 32 * es + 8 * c8);
        }
      }
      __syncthreads();
#pragma unroll
      for (int i = 0; i < 3; i++) {
        int slot = i * 256 + tid;
        if (slot < 640) {
          int row = slot >> 2, c8 = slot & 3;
          *(uint4*)(sm + RK_O + row * 40 + 8 * c8) = rkr[i];
        }
      }
      __syncthreads();
      bf16x8 qh = *(const bf16x8*)(sm + QHI_O + (16 * qt + lr) * 136 + 32 * es + 8 * lg);
      bf16x8 ql = *(const bf16x8*)(sm + QLO_O + (16 * qt + lr) * 136 + 32 * es + 8 * lg);
#pragma unroll
      for (int j = 0; j < 5; j++) {
        bf16x8 kv = *(const bf16x8*)(sm + RK_O + (16 * (ktb + j) + lr) * 40 + 8 * lg);
        acc_s[j] = MF(qh, kv, acc_s[j]);
        acc_s[j] = MF(ql, kv, acc_s[j]);
      }
    }
  }

  __syncthreads();
#pragma unroll
  for (int j = 0; j < 5; j++)
#pragma unroll
    for (int r = 0; r < 4; r++) {
      int row = 16 * qt + 4 * lg + r;
      int col = 16 * (ktb + j) + lr;
      smf[row * 172 + col] = acc_s[j][r];
    }
  __syncthreads();

  {
    const int row = tid >> 3, l8 = tid & 7;
    int clo = row;          { int t2 = 64 - q0;            if (t2 > clo) clo = t2; }
    int chi = row + 128;    { int t2 = 2047 + 64 - q0;     if (t2 < chi) chi = t2; }
    float m = -1e30f;
    for (int c = l8; c < 160; c += 8)
      if (c >= clo && c <= chi) m = fmaxf(m, smf[row * 172 + c]);
    m = fmaxf(m, __shfl_xor(m, 1));
    m = fmaxf(m, __shfl_xor(m, 2));
    m = fmaxf(m, __shfl_xor(m, 4));
    float ssum = 0.f;
    for (int c = l8; c < 160; c += 8) {
      float e = (c >= clo && c <= chi) ? __expf(smf[row * 172 + c] - m) : 0.f;
      smf[row * 172 + c] = e;
      ssum += e;
    }
    ssum += __shfl_xor(ssum, 1);
    ssum += __shfl_xor(ssum, 2);
    ssum += __shfl_xor(ssum, 4);
    float rinv = 1.f / ssum;
    for (int c = l8; c < 160; c += 8)
      sm[PBF_O + row * 168 + c] = f2bf(smf[row * 172 + c] * rinv);
  }
  __syncthreads();

  const int dtl = (w & 1) * 2;
  bf16x8 pa[5];
#pragma unroll
  for (int ks = 0; ks < 5; ks++)
    pa[ks] = *(const bf16x8*)(sm + PBF_O + (16 * qt + lr) * 168 + 32 * ks + 8 * lg);

  for (int dc = 0; dc < 16; dc++) {
    const int d0 = dc * 64;
    uint4 vr[5];
#pragma unroll
    for (int i = 0; i < 5; i++) {
      int slot = i * 256 + tid;
      int k = slot >> 3, g = slot & 7;
      int kk = q0 - 64 + k;
      kk = kk < 0 ? 0 : (kk > 2047 ? 2047 : kk);
      vr[i] = *(const uint4*)(reprB + baseR + (size_t)kk * 1024 + d0 + 8 * g);
    }
    __syncthreads();
#pragma unroll
    for (int i = 0; i < 5; i++) {
      int slot = i * 256 + tid;
      int k = slot >> 3, g = slot & 7;
      const unsigned short* pv = (const unsigned short*)&vr[i];
#pragma unroll
      for (int j2 = 0; j2 < 8; j2++)
        sm[VT_O + (8 * g + j2) * 168 + k] = pv[j2];
    }
    __syncthreads();
    f32x4 ra0 = (f32x4){0.f, 0.f, 0.f, 0.f};
    f32x4 ra1 = (f32x4){0.f, 0.f, 0.f, 0.f};
#pragma unroll
    for (int ks = 0; ks < 5; ks++) {
      bf16x8 v0 = *(const bf16x8*)(sm + VT_O + (16 * dtl + lr) * 168 + 32 * ks + 8 * lg);
      bf16x8 v1 = *(const bf16x8*)(sm + VT_O + (16 * (dtl + 1) + lr) * 168 + 32 * ks + 8 * lg);
      ra0 = MF(pa[ks], v0, ra0);
      ra1 = MF(pa[ks], v1, ra1);
    }
#pragma unroll
    for (int r = 0; r < 4; r++) {
      int qg = q0 + 16 * qt + 4 * lg + r;
      size_t base = baseR + (size_t)qg * 1024 + d0;
      int dg0 = 16 * dtl + lr, dg1 = 16 * (dtl + 1) + lr;
      float o0 = bfu(reprB[base + dg0]) + fmaxf(ra0[r], 0.f);
      float o1 = bfu(reprB[base + dg1]) + fmaxf(ra1[r], 0.f);
      outB[base + dg0] = f2bf(o0);
      outB[base + dg1] = f2bf(o1);
    }
  }
}

// ---------------------------------------------------------------------------
// fp32-data MFMA kernel: bf16 hi/lo split (3-term) for Q- and S-GEMMs,
// single-bf16 P and V for PV. Accuracy ~1e-4 absolute on out.
//
// LDS layout (ushort units), phase-disjoint aliasing:
//  Phase A d-loop: WTSH [128][72] @0, WTSL @9216, RQSH [32][72] @18432,
//                  RQSL @20736
//  Phase A3:       RKH [160][40] @0 (aliases WTS), RKL @6400
//  persistent A:   QHI [32][136] @23040, QLO @27392
//  Phase B:        Sls f32 [32][172] @byte0 (aliases WTS/RK, dead),
//                  PBF [32][168] @11008, VT [64][168] @16384 (aliases QHI/QLO, dead)
// Total 31744 ushorts = 63488 B -> 2 blocks/CU.
// ---------------------------------------------------------------------------
#define FWTSH_O 0
#define FWTSL_O 9216
#define FRQSH_O 18432
#define FRQSL_O 20736
#define FRKH_O  0
#define FRKL_O  6400
#define FQHI_O  23040
#define FQLO_O  27392
#define FPBF_O  11008
#define FVT_O   16384
#define FSMEMU  31744

__global__ void __launch_bounds__(256, 2) attn_mfma_f32(
    const float* __restrict__ reprF,
    const unsigned short* __restrict__ WtH,
    const unsigned short* __restrict__ WtL,
    float* __restrict__ outF) {
  if (data_is_bf16((const unsigned short*)reprF)) return;   // bf16 data -> other kernel

  __shared__ alignas(16) unsigned short sm[FSMEMU];
  float* smf = (float*)sm;

  const int tid = threadIdx.x;
  const int w = tid >> 6, l = tid & 63, lr = l & 15, lg = l >> 4;
  const int b = blockIdx.y, q0 = blockIdx.x * 32;
  const size_t baseR = (size_t)b * 2048 * 1024;
  const int qt = w >> 1;           // q-tile (0/1) this wave owns for S/PV
  const int ktb = (w & 1) * 5;     // S key-tile base

  f32x4 acc_s[5];
#pragma unroll
  for (int j = 0; j < 5; j++) acc_s[j] = (f32x4){0.f, 0.f, 0.f, 0.f};

  // ---------------- Phase A: Q = R@Wt^T (hi/lo 3-term) + S accumulate ------
  for (int ec = 0; ec < 8; ec++) {
    const int e0 = ec * 128;
    f32x4 acc_q[2][2];
#pragma unroll
    for (int i = 0; i < 2; i++)
#pragma unroll
      for (int j = 0; j < 2; j++) acc_q[i][j] = (f32x4){0.f, 0.f, 0.f, 0.f};

    for (int s = 0; s < 16; s++) {
      const int d0 = s * 64;
      uint4 wthr[4], wtlr[4];
      float4 rq4[2];
#pragma unroll
      for (int i = 0; i < 4; i++) {
        int slot = i * 256 + tid, row = slot >> 3, c8 = slot & 7;
        size_t off = (size_t)(e0 + row) * 1024 + d0 + 8 * c8;
        wthr[i] = *(const uint4*)(WtH + off);
        wtlr[i] = *(const uint4*)(WtL + off);
      }
#pragma unroll
      for (int i = 0; i < 2; i++) {
        int slot = i * 256 + tid, row = slot >> 4, cf = slot & 15;
        rq4[i] = *(const float4*)(reprF + baseR + (size_t)(q0 + row) * 1024 + d0 + 4 * cf);
      }
      __syncthreads();   // previous stage's LDS reads complete
#pragma unroll
      for (int i = 0; i < 4; i++) {
        int slot = i * 256 + tid, row = slot >> 3, c8 = slot & 7;
        *(uint4*)(sm + FWTSH_O + row * 72 + 8 * c8) = wthr[i];
        *(uint4*)(sm + FWTSL_O + row * 72 + 8 * c8) = wtlr[i];
      }
#pragma unroll
      for (int i = 0; i < 2; i++) {
        int slot = i * 256 + tid, row = slot >> 4, cf = slot & 15;
        ushort4 h4, l4;
        hilo(rq4[i].x, h4.x, l4.x); hilo(rq4[i].y, h4.y, l4.y);
        hilo(rq4[i].z, h4.z, l4.z); hilo(rq4[i].w, h4.w, l4.w);
        *(ushort4*)(sm + FRQSH_O + row * 72 + 4 * cf) = h4;
        *(ushort4*)(sm + FRQSL_O + row * 72 + 4 * cf) = l4;
      }
      __syncthreads();   // writes visible
#pragma unroll
      for (int h = 0; h < 2; h++) {
        bf16x8 ah0 = *(const bf16x8*)(sm + FRQSH_O + (lr) * 72 + 32 * h + 8 * lg);
        bf16x8 ah1 = *(const bf16x8*)(sm + FRQSH_O + (16 + lr) * 72 + 32 * h + 8 * lg);
        bf16x8 al0 = *(const bf16x8*)(sm + FRQSL_O + (lr) * 72 + 32 * h + 8 * lg);
        bf16x8 al1 = *(const bf16x8*)(sm + FRQSL_O + (16 + lr) * 72 + 32 * h + 8 * lg);
        bf16x8 bh0 = *(const bf16x8*)(sm + FWTSH_O + (32 * w + lr) * 72 + 32 * h + 8 * lg);
        bf16x8 bh1 = *(const bf16x8*)(sm + FWTSH_O + (32 * w + 16 + lr) * 72 + 32 * h + 8 * lg);
        bf16x8 bl0 = *(const bf16x8*)(sm + FWTSL_O + (32 * w + lr) * 72 + 32 * h + 8 * lg);
        bf16x8 bl1 = *(const bf16x8*)(sm + FWTSL_O + (32 * w + 16 + lr) * 72 + 32 * h + 8 * lg);
        acc_q[0][0] = MF(ah0, bh0, acc_q[0][0]);
        acc_q[0][1] = MF(ah0, bh1, acc_q[0][1]);
        acc_q[1][0] = MF(ah1, bh0, acc_q[1][0]);
        acc_q[1][1] = MF(ah1, bh1, acc_q[1][1]);
        acc_q[0][0] = MF(ah0, bl0, acc_q[0][0]);
        acc_q[0][1] = MF(ah0, bl1, acc_q[0][1]);
        acc_q[1][0] = MF(ah1, bl0, acc_q[1][0]);
        acc_q[1][1] = MF(ah1, bl1, acc_q[1][1]);
        acc_q[0][0] = MF(al0, bh0, acc_q[0][0]);
        acc_q[0][1] = MF(al0, bh1, acc_q[0][1]);
        acc_q[1][0] = MF(al1, bh0, acc_q[1][0]);
        acc_q[1][1] = MF(al1, bh1, acc_q[1][1]);
      }
    }

    // A2: Q accumulators -> QHI/QLO (hi/lo bf16 split)
#pragma unroll
    for (int qq = 0; qq < 2; qq++)
#pragma unroll
      for (int et = 0; et < 2; et++)
#pragma unroll
        for (int r = 0; r < 4; r++) {
          int row = 16 * qq + 4 * lg + r;
          int col = 32 * w + 16 * et + lr;
          float v = acc_q[qq][et][r];
          unsigned short hi, lo;
          hilo(v, hi, lo);
          sm[FQHI_O + row * 136 + col] = hi;
          sm[FQLO_O + row * 136 + col] = lo;
        }

    // A3: S += Qchunk @ K^T (hi/lo 3-term), 4 e-slices of 32
    for (int es = 0; es < 4; es++) {
      float4 rk4[5];
#pragma unroll
      for (int i = 0; i < 5; i++) {
        int slot = i * 256 + tid;
        int row = slot >> 3, cf = slot & 7;
        int kk = q0 - 64 + row;
        kk = kk < 0 ? 0 : (kk > 2047 ? 2047 : kk);
        rk4[i] = *(const float4*)(reprF + baseR + (size_t)kk * 1024 + e0 + 32 * es + 4 * cf);
      }
      __syncthreads();   // QHI writes (es==0) / previous RK reads done
#pragma unroll
      for (int i = 0; i < 5; i++) {
        int slot = i * 256 + tid;
        int row = slot >> 3, cf = slot & 7;
        ushort4 h4, l4;
        hilo(rk4[i].x, h4.x, l4.x); hilo(rk4[i].y, h4.y, l4.y);
        hilo(rk4[i].z, h4.z, l4.z); hilo(rk4[i].w, h4.w, l4.w);
        *(ushort4*)(sm + FRKH_O + row * 40 + 4 * cf) = h4;
        *(ushort4*)(sm + FRKL_O + row * 40 + 4 * cf) = l4;
      }
      __syncthreads();
      bf16x8 qh = *(const bf16x8*)(sm + FQHI_O + (16 * qt + lr) * 136 + 32 * es + 8 * lg);
      bf16x8 ql = *(const bf16x8*)(sm + FQLO_O + (16 * qt + lr) * 136 + 32 * es + 8 * lg);
#pragma unroll
      for (int j = 0; j < 5; j++) {
        bf16x8 kh = *(const bf16x8*)(sm + FRKH_O + (16 * (ktb + j) + lr) * 40 + 8 * lg);
        bf16x8 kl = *(const bf16x8*)(sm + FRKL_O + (16 * (ktb + j) + lr) * 40 + 8 * lg);
        acc_s[j] = MF(qh, kh, acc_s[j]);
        acc_s[j] = MF(qh, kl, acc_s[j]);
        acc_s[j] = MF(ql, kh, acc_s[j]);
      }
    }
  }

  __syncthreads();
  // scores -> Sls (f32, pitch 172) @0 (WTS/RK dead)
#pragma unroll
  for (int j = 0; j < 5; j++)
#pragma unroll
    for (int r = 0; r < 4; r++) {
      int row = 16 * qt + 4 * lg + r;
      int col = 16 * (ktb + j) + lr;
      smf[row * 172 + col] = acc_s[j][r];
    }
  __syncthreads();

  // masked softmax (8 lanes/row), probs -> PBF bf16
  {
    const int row = tid >> 3, l8 = tid & 7;
    int clo = row;          { int t2 = 64 - q0;            if (t2 > clo) clo = t2; }
    int chi = row + 128;    { int t2 = 2047 + 64 - q0;     if (t2 < chi) chi = t2; }
    float m = -1e30f;
    for (int c = l8; c < 160; c += 8)
      if (c >= clo && c <= chi) m = fmaxf(m, smf[row * 172 + c]);
    m = fmaxf(m, __shfl_xor(m, 1));
    m = fmaxf(m, __shfl_xor(m, 2));
    m = fmaxf(m, __shfl_xor(m, 4));
    float ssum = 0.f;
    for (int c = l8; c < 160; c += 8) {
      float e = (c >= clo && c <= chi) ? __expf(smf[row * 172 + c] - m) : 0.f;
      smf[row * 172 + c] = e;
      ssum += e;
    }
    ssum += __shfl_xor(ssum, 1);
    ssum += __shfl_xor(ssum, 2);
    ssum += __shfl_xor(ssum, 4);
    float rinv = 1.f / ssum;
    for (int c = l8; c < 160; c += 8)
      sm[FPBF_O + row * 168 + c] = f2bf(smf[row * 172 + c] * rinv);
  }
  __syncthreads();

  // ---------------- Phase B: ra = P @ V (single-bf16), out = repr+relu -----
  const int dtl = (w & 1) * 2;
  bf16x8 pa[5];
#pragma unroll
  for (int ks = 0; ks < 5; ks++)
    pa[ks] = *(const bf16x8*)(sm + FPBF_O + (16 * qt + lr) * 168 + 32 * ks + 8 * lg);

  for (int dc = 0; dc < 16; dc++) {
    const int d0 = dc * 64;
    float4 vr4[10];
#pragma unroll
    for (int i = 0; i < 10; i++) {
      int slot = i * 256 + tid;          // 2560 float4 slots
      int k = slot >> 4, g = slot & 15;
      int kk = q0 - 64 + k;
      kk = kk < 0 ? 0 : (kk > 2047 ? 2047 : kk);
      vr4[i] = *(const float4*)(reprF + baseR + (size_t)kk * 1024 + d0 + 4 * g);
    }
    __syncthreads();   // previous chunk's VT reads done
#pragma unroll
    for (int i = 0; i < 10; i++) {
      int slot = i * 256 + tid;
      int k = slot >> 4, g = slot & 15;
      sm[FVT_O + (4 * g + 0) * 168 + k] = f2bf(vr4[i].x);
      sm[FVT_O + (4 * g + 1) * 168 + k] = f2bf(vr4[i].y);
      sm[FVT_O + (4 * g + 2) * 168 + k] = f2bf(vr4[i].z);
      sm[FVT_O + (4 * g + 3) * 168 + k] = f2bf(vr4[i].w);
    }
    __syncthreads();
    f32x4 ra0 = (f32x4){0.f, 0.f, 0.f, 0.f};
    f32x4 ra1 = (f32x4){0.f, 0.f, 0.f, 0.f};
#pragma unroll
    for (int ks = 0; ks < 5; ks++) {
      bf16x8 v0 = *(const bf16x8*)(sm + FVT_O + (16 * dtl + lr) * 168 + 32 * ks + 8 * lg);
      bf16x8 v1 = *(const bf16x8*)(sm + FVT_O + (16 * (dtl + 1) + lr) * 168 + 32 * ks + 8 * lg);
      ra0 = MF(pa[ks], v0, ra0);
      ra1 = MF(pa[ks], v1, ra1);
    }
#pragma unroll
    for (int r = 0; r < 4; r++) {
      int qg = q0 + 16 * qt + 4 * lg + r;
      size_t base = baseR + (size_t)qg * 1024 + d0;
      int dg0 = 16 * dtl + lr, dg1 = 16 * (dtl + 1) + lr;
      outF[base + dg0] = reprF[base + dg0] + fmaxf(ra0[r], 0.f);
      outF[base + dg1] = reprF[base + dg1] + fmaxf(ra1[r], 0.f);
    }
  }
}

extern "C" void kernel_launch(void* const* d_in, const int* in_sizes, int n_in,
                              void* d_out, int out_size, void* d_ws, size_t ws_size,
                              hipStream_t stream) {
  const void* repr = d_in[0];
  const void* W    = d_in[1];
  dim3 grid(SEQL / QT, NB);   // (64, 8) = 512 blocks

  const bool use_mfma = (d_ws != nullptr) && (ws_size >= (size_t)4 * 1024 * 1024);
  if (use_mfma) {
    tposeW2<<<dim3(256), dim3(256), 0, stream>>>(repr, W, d_ws);
    attn_mfma<<<grid, dim3(256), 0, stream>>>(
        (const unsigned short*)repr, (const unsigned short*)d_ws, (unsigned short*)d_out);
    attn_mfma_f32<<<grid, dim3(256), 0, stream>>>(
        (const float*)repr, (const unsigned short*)d_ws,
        (const unsigned short*)d_ws + (1u << 20), (float*)d_out);
  } else {
    attn_fused<true><<<grid, dim3(256), 0, stream>>>(repr, W, d_out);
    attn_fused<false><<<grid, dim3(256), 0, stream>>>(repr, W, d_out);
  }
}

// Round 4
// 556.615 us; speedup vs baseline: 2.3079x; 1.0398x over previous
//
#include <hip/hip_runtime.h>

// AttentionWindow: out = repr + relu(softmax_masked((repr@W)@repr^T) @ repr)
// BATCH=8, SEQ=2048, HIDDEN=1024, window half-width 64 (|i-j|>64 masked).
//
// Three data modes, detected per-block by a uniform sniff of repr's bytes:
//   bf16 data  -> attn_mfma      (verified; unchanged)
//   fp32 data  -> attn_mfma_f32  (bf16 hi/lo split MFMA; R4: T14 pipelined
//                                 staging + XOR-swizzled V-transpose)
//   no workspace fallback -> proven VALU pair.

#define SEQL 2048
#define HID  1024
#define NB   8
#define QT   32
#define KT   160
#define DCO  128
#define EC   32
#define DS   32
#define RP   36
#define WP   132
#define QP   132
#define KP   36
#define SP   161

#define RS_OFF  0
#define WS_OFF  1152
#define KS_OFF  0
#define QCS_OFF 5760
#define SC_OFF  5760
#define SMEM_F  10912

__device__ __forceinline__ float bfu(unsigned int lo16) {
  union { unsigned int i; float f; } v; v.i = lo16 << 16; return v.f;
}
__device__ __forceinline__ unsigned short f2bf(float f) {
  union { float f; unsigned int i; } v; v.f = f;
  unsigned int r = v.i + 0x7FFFu + ((v.i >> 16) & 1u);   // RNE
  return (unsigned short)(r >> 16);
}
__device__ __forceinline__ void hilo(float v, unsigned short& h, unsigned short& l) {
  h = f2bf(v);
  l = f2bf(v - bfu(h));
}

// Uniform dtype sniff (thread-invariant).
__device__ bool data_is_bf16(const unsigned short* u) {
  int cnt = 0;
  for (int i = 0; i < 256; i++) {
    int e = (u[i] >> 7) & 0xFF;
    if (e >= 107 && e <= 131) cnt++;
  }
  return cnt >= 230;
}

template<bool BF16>
__device__ __forceinline__ float4 ld4(const void* p, size_t idx) {
  if (BF16) {
    uint2 u = *(const uint2*)((const unsigned short*)p + idx);
    float4 r;
    r.x = bfu(u.x & 0xFFFFu); r.y = bfu(u.x >> 16);
    r.z = bfu(u.y & 0xFFFFu); r.w = bfu(u.y >> 16);
    return r;
  } else {
    return *(const float4*)((const float*)p + idx);
  }
}

template<bool BF16>
__device__ __forceinline__ void st4(void* p, size_t idx, float4 v) {
  if (BF16) {
    ushort4 o;
    o.x = f2bf(v.x); o.y = f2bf(v.y); o.z = f2bf(v.z); o.w = f2bf(v.w);
    *(ushort4*)((unsigned short*)p + idx) = o;
  } else {
    *(float4*)((float*)p + idx) = v;
  }
}

__device__ __forceinline__ void fma4(float4& q, float a, const float4& w) {
  q.x += a * w.x; q.y += a * w.y; q.z += a * w.z; q.w += a * w.w;
}

// ---------------------------------------------------------------------------
// OLD proven VALU kernel (fallback when no workspace)
// ---------------------------------------------------------------------------
template<bool BF16>
__global__ void __launch_bounds__(256) attn_fused(
    const void* __restrict__ reprv, const void* __restrict__ Wv,
    void* __restrict__ outv) {
  if (data_is_bf16((const unsigned short*)reprv) != BF16) return;

  __shared__ float smem[SMEM_F];
  const int tid = threadIdx.x;
  const int b = blockIdx.y;
  const int q0 = blockIdx.x * QT;
  const size_t baseR = (size_t)b * SEQL * HID;

  const int tx = tid & 31, ty = tid >> 5;

  float acc[4][5];
#pragma unroll
  for (int i = 0; i < 4; i++)
#pragma unroll
    for (int j = 0; j < 5; j++) acc[i][j] = 0.f;

  for (int d0 = 0; d0 < HID; d0 += DCO) {
    float4 qc[4];
#pragma unroll
    for (int i = 0; i < 4; i++) qc[i] = make_float4(0.f, 0.f, 0.f, 0.f);

    for (int e0 = 0; e0 < HID; e0 += EC) {
      {
        int row = tid >> 3, cg = tid & 7;
        float4 v = ld4<BF16>(reprv, baseR + (size_t)(q0 + row) * HID + e0 + 4 * cg);
        *(float4*)&smem[RS_OFF + row * RP + 4 * cg] = v;
      }
#pragma unroll
      for (int i2 = 0; i2 < 4; i2++) {
        int f = i2 * 256 + tid;
        int row = f >> 5, cg = f & 31;
        float4 v = ld4<BF16>(Wv, (size_t)(e0 + row) * HID + d0 + 4 * cg);
        *(float4*)&smem[WS_OFF + row * WP + 4 * cg] = v;
      }
      __syncthreads();
#pragma unroll
      for (int ee = 0; ee < EC; ee += 4) {
        float4 rv[4];
#pragma unroll
        for (int i = 0; i < 4; i++)
          rv[i] = *(const float4*)&smem[RS_OFF + (ty + 8 * i) * RP + ee];
        {
          float4 wv = *(const float4*)&smem[WS_OFF + (ee + 0) * WP + 4 * tx];
          fma4(qc[0], rv[0].x, wv); fma4(qc[1], rv[1].x, wv);
          fma4(qc[2], rv[2].x, wv); fma4(qc[3], rv[3].x, wv);
        }
        {
          float4 wv = *(const float4*)&smem[WS_OFF + (ee + 1) * WP + 4 * tx];
          fma4(qc[0], rv[0].y, wv); fma4(qc[1], rv[1].y, wv);
          fma4(qc[2], rv[2].y, wv); fma4(qc[3], rv[3].y, wv);
        }
        {
          float4 wv = *(const float4*)&smem[WS_OFF + (ee + 2) * WP + 4 * tx];
          fma4(qc[0], rv[0].z, wv); fma4(qc[1], rv[1].z, wv);
          fma4(qc[2], rv[2].z, wv); fma4(qc[3], rv[3].z, wv);
        }
        {
          float4 wv = *(const float4*)&smem[WS_OFF + (ee + 3) * WP + 4 * tx];
          fma4(qc[0], rv[0].w, wv); fma4(qc[1], rv[1].w, wv);
          fma4(qc[2], rv[2].w, wv); fma4(qc[3], rv[3].w, wv);
        }
      }
      __syncthreads();
    }

#pragma unroll
    for (int i = 0; i < 4; i++)
      *(float4*)&smem[QCS_OFF + (ty + 8 * i) * QP + 4 * tx] = qc[i];

    for (int s = 0; s < DCO; s += DS) {
#pragma unroll
      for (int i2 = 0; i2 < 5; i2++) {
        int f = i2 * 256 + tid;
        int row = f >> 3, cg = f & 7;
        int kk = q0 - 64 + row;
        kk = kk < 0 ? 0 : (kk > SEQL - 1 ? SEQL - 1 : kk);
        float4 v = ld4<BF16>(reprv, baseR + (size_t)kk * HID + d0 + s + 4 * cg);
        *(float4*)&smem[KS_OFF + row * KP + 4 * cg] = v;
      }
      __syncthreads();
#pragma unroll
      for (int dd = 0; dd < DS; dd += 4) {
        float4 qv[4];
#pragma unroll
        for (int i = 0; i < 4; i++)
          qv[i] = *(const float4*)&smem[QCS_OFF + (ty + 8 * i) * QP + s + dd];
#pragma unroll
        for (int j = 0; j < 5; j++) {
          float4 kv = *(const float4*)&smem[KS_OFF + (tx + 32 * j) * KP + dd];
#pragma unroll
          for (int i = 0; i < 4; i++)
            acc[i][j] += qv[i].x * kv.x + qv[i].y * kv.y + qv[i].z * kv.z + qv[i].w * kv.w;
        }
      }
      __syncthreads();
    }
  }

#pragma unroll
  for (int i = 0; i < 4; i++)
#pragma unroll
    for (int j = 0; j < 5; j++)
      smem[SC_OFF + (ty + 8 * i) * SP + tx + 32 * j] = acc[i][j];
  __syncthreads();

  {
    const int row = tid >> 3, l8 = tid & 7;
    int clo = row;          { int t = 64 - q0;            if (t > clo) clo = t; }
    int chi = row + 128;    { int t = SEQL - 1 + 64 - q0; if (t < chi) chi = t; }
    float m = -1e30f;
    for (int c = l8; c < KT; c += 8)
      if (c >= clo && c <= chi) m = fmaxf(m, smem[SC_OFF + row * SP + c]);
    m = fmaxf(m, __shfl_xor(m, 1));
    m = fmaxf(m, __shfl_xor(m, 2));
    m = fmaxf(m, __shfl_xor(m, 4));
    float ssum = 0.f;
    for (int c = l8; c < KT; c += 8) {
      float e = (c >= clo && c <= chi) ? __expf(smem[SC_OFF + row * SP + c] - m) : 0.f;
      smem[SC_OFF + row * SP + c] = e;
      ssum += e;
    }
    ssum += __shfl_xor(ssum, 1);
    ssum += __shfl_xor(ssum, 2);
    ssum += __shfl_xor(ssum, 4);
    float rinv = 1.f / ssum;
    for (int c = l8; c < KT; c += 8) smem[SC_OFF + row * SP + c] *= rinv;
  }
  __syncthreads();

  const int rr = tid >> 3, dq = tid & 7;
  for (int d0 = 0; d0 < HID; d0 += DS) {
#pragma unroll
    for (int i2 = 0; i2 < 5; i2++) {
      int f = i2 * 256 + tid;
      int row = f >> 3, cg = f & 7;
      int kk = q0 - 64 + row;
      kk = kk < 0 ? 0 : (kk > SEQL - 1 ? SEQL - 1 : kk);
      float4 v = ld4<BF16>(reprv, baseR + (size_t)kk * HID + d0 + 4 * cg);
      *(float4*)&smem[KS_OFF + row * KP + 4 * cg] = v;
    }
    __syncthreads();
    float4 o = make_float4(0.f, 0.f, 0.f, 0.f);
#pragma unroll 4
    for (int c = 0; c < KT; c++) {
      float4 kv = *(const float4*)&smem[KS_OFF + c * KP + 4 * dq];
      float p = smem[SC_OFF + rr * SP + c];
      o.x += p * kv.x; o.y += p * kv.y; o.z += p * kv.z; o.w += p * kv.w;
    }
    size_t goff = baseR + (size_t)(q0 + rr) * HID + d0 + 4 * dq;
    float4 rv = ld4<BF16>(reprv, goff);
    float4 ov;
    ov.x = rv.x + fmaxf(o.x, 0.f);
    ov.y = rv.y + fmaxf(o.y, 0.f);
    ov.z = rv.z + fmaxf(o.z, 0.f);
    ov.w = rv.w + fmaxf(o.w, 0.f);
    st4<BF16>(outv, goff, ov);
    __syncthreads();
  }
}

// ---------------------------------------------------------------------------
// MFMA common
// ---------------------------------------------------------------------------
typedef float f32x4 __attribute__((ext_vector_type(4)));
typedef short bf16x8 __attribute__((ext_vector_type(8)));

#define MF(a_, b_, c_) __builtin_amdgcn_mfma_f32_16x16x32_bf16((a_), (b_), (c_), 0, 0, 0)

// W-transpose (dual-mode). bf16 data: Wt bf16 @ws0 (2MB, exact).
// fp32 data: WtHi @ws0 (2MB) + WtLo @ws+2MB (bf16 hi/lo split of W^T).
__global__ void __launch_bounds__(256) tposeW2(
    const void* __restrict__ reprv, const void* __restrict__ Wv,
    void* __restrict__ wsv) {
  const bool isbf = data_is_bf16((const unsigned short*)reprv);
  __shared__ alignas(16) unsigned char twsb[64 * 68 * 4];
  const int t = threadIdx.x;
  const int d0 = (blockIdx.x & 15) * 64, e0 = (blockIdx.x >> 4) * 64;
  if (isbf) {
    unsigned short* tl = (unsigned short*)twsb;
    const unsigned short* WB = (const unsigned short*)Wv;
    unsigned short* WtB = (unsigned short*)wsv;
#pragma unroll
    for (int i = 0; i < 2; i++) {
      int slot = i * 256 + t, row = slot >> 3, c8 = slot & 7;
      *(uint4*)(tl + row * 72 + 8 * c8) =
          *(const uint4*)(WB + (size_t)(d0 + row) * 1024 + e0 + 8 * c8);
    }
    __syncthreads();
#pragma unroll
    for (int i = 0; i < 2; i++) {
      int slot = i * 256 + t, er = slot >> 3, c8 = slot & 7;
      unsigned short v[8];
#pragma unroll
      for (int j = 0; j < 8; j++) v[j] = tl[(8 * c8 + j) * 72 + er];
      *(uint4*)(WtB + (size_t)(e0 + er) * 1024 + d0 + 8 * c8) = *(const uint4*)v;
    }
  } else {
    float* tlf = (float*)twsb;
    const float* WF = (const float*)Wv;
    unsigned short* WtH = (unsigned short*)wsv;
    unsigned short* WtL = WtH + (1u << 20);   // +2 MB
#pragma unroll
    for (int i = 0; i < 4; i++) {
      int slot = i * 256 + t, row = slot >> 4, cf = slot & 15;
      *(float4*)&tlf[row * 68 + 4 * cf] =
          *(const float4*)(WF + (size_t)(d0 + row) * 1024 + e0 + 4 * cf);
    }
    __syncthreads();
#pragma unroll
    for (int i = 0; i < 2; i++) {
      int slot = i * 256 + t, er = slot >> 3, c8 = slot & 7;
      unsigned short vh[8], vl[8];
#pragma unroll
      for (int j = 0; j < 8; j++) {
        float v = tlf[(8 * c8 + j) * 68 + er];
        hilo(v, vh[j], vl[j]);
      }
      *(uint4*)(WtH + (size_t)(e0 + er) * 1024 + d0 + 8 * c8) = *(const uint4*)vh;
      *(uint4*)(WtL + (size_t)(e0 + er) * 1024 + d0 + 8 * c8) = *(const uint4*)vl;
    }
  }
}

// ---------------------------------------------------------------------------
// bf16-data MFMA kernel (round-1 verified, unchanged)
// ---------------------------------------------------------------------------
#define WTS_O 0
#define RQS_O 9216
#define RK_O  11520
#define QHI_O 17920
#define QLO_O 22272
#define PBF_O 11008
#define VT_O  16384
#define SMEMU 27136

__global__ void __launch_bounds__(256, 2) attn_mfma(
    const unsigned short* __restrict__ reprB,
    const unsigned short* __restrict__ WtB,
    unsigned short* __restrict__ outB) {
  if (!data_is_bf16(reprB)) return;

  __shared__ alignas(16) unsigned short sm[SMEMU];
  float* smf = (float*)sm;

  const int tid = threadIdx.x;
  const int w = tid >> 6, l = tid & 63, lr = l & 15, lg = l >> 4;
  const int b = blockIdx.y, q0 = blockIdx.x * 32;
  const size_t baseR = (size_t)b * 2048 * 1024;
  const int qt = w >> 1;
  const int ktb = (w & 1) * 5;

  f32x4 acc_s[5];
#pragma unroll
  for (int j = 0; j < 5; j++) acc_s[j] = (f32x4){0.f, 0.f, 0.f, 0.f};

  for (int ec = 0; ec < 8; ec++) {
    const int e0 = ec * 128;
    f32x4 acc_q[2][2];
#pragma unroll
    for (int i = 0; i < 2; i++)
#pragma unroll
      for (int j = 0; j < 2; j++) acc_q[i][j] = (f32x4){0.f, 0.f, 0.f, 0.f};

    for (int s = 0; s < 16; s++) {
      const int d0 = s * 64;
      uint4 wtr[4], rqr;
#pragma unroll
      for (int i = 0; i < 4; i++) {
        int slot = i * 256 + tid, row = slot >> 3, c8 = slot & 7;
        wtr[i] = *(const uint4*)(WtB + (size_t)(e0 + row) * 1024 + d0 + 8 * c8);
      }
      {
        int row = tid >> 3, c8 = tid & 7;
        rqr = *(const uint4*)(reprB + baseR + (size_t)(q0 + row) * 1024 + d0 + 8 * c8);
      }
      __syncthreads();
#pragma unroll
      for (int i = 0; i < 4; i++) {
        int slot = i * 256 + tid, row = slot >> 3, c8 = slot & 7;
        *(uint4*)(sm + WTS_O + row * 72 + 8 * c8) = wtr[i];
      }
      {
        int row = tid >> 3, c8 = tid & 7;
        *(uint4*)(sm + RQS_O + row * 72 + 8 * c8) = rqr;
      }
      __syncthreads();
#pragma unroll
      for (int h = 0; h < 2; h++) {
        bf16x8 a0 = *(const bf16x8*)(sm + RQS_O + (lr) * 72 + 32 * h + 8 * lg);
        bf16x8 a1 = *(const bf16x8*)(sm + RQS_O + (16 + lr) * 72 + 32 * h + 8 * lg);
        bf16x8 b0 = *(const bf16x8*)(sm + WTS_O + (32 * w + lr) * 72 + 32 * h + 8 * lg);
        bf16x8 b1 = *(const bf16x8*)(sm + WTS_O + (32 * w + 16 + lr) * 72 + 32 * h + 8 * lg);
        acc_q[0][0] = MF(a0, b0, acc_q[0][0]);
        acc_q[0][1] = MF(a0, b1, acc_q[0][1]);
        acc_q[1][0] = MF(a1, b0, acc_q[1][0]);
        acc_q[1][1] = MF(a1, b1, acc_q[1][1]);
      }
    }

#pragma unroll
    for (int qq = 0; qq < 2; qq++)
#pragma unroll
      for (int et = 0; et < 2; et++)
#pragma unroll
        for (int r = 0; r < 4; r++) {
          int row = 16 * qq + 4 * lg + r;
          int col = 32 * w + 16 * et + lr;
          float v = acc_q[qq][et][r];
          unsigned short hi = f2bf(v);
          sm[QHI_O + row * 136 + col] = hi;
          sm[QLO_O + row * 136 + col] = f2bf(v - bfu(hi));
        }

    for (int es = 0; es < 4; es++) {
      uint4 rkr[3];
#pragma unroll
      for (int i = 0; i < 3; i++) {
        int slot = i * 256 + tid;
        if (slot < 640) {
          int row = slot >> 2, c8 = slot & 3;
          int kk = q0 - 64 + row;
          kk = kk < 0 ? 0 : (kk > 2047 ? 2047 : kk);
          rkr[i] = *(const uint4*)(reprB + baseR + (size_t)kk * 1024 + e0 + 32 * es + 8 * c8);
        }
      }
      __syncthreads();
#pragma unroll
      for (int i = 0; i < 3; i++) {
        int slot = i * 256 + tid;
        if (slot < 640) {
          int row = slot >> 2, c8 = slot & 3;
          *(uint4*)(sm + RK_O + row * 40 + 8 * c8) = rkr[i];
        }
      }
      __syncthreads();
      bf16x8 qh = *(const bf16x8*)(sm + QHI_O + (16 * qt + lr) * 136 + 32 * es + 8 * lg);
      bf16x8 ql = *(const bf16x8*)(sm + QLO_O + (16 * qt + lr) * 136 + 32 * es + 8 * lg);
#pragma unroll
      for (int j = 0; j < 5; j++) {
        bf16x8 kv = *(const bf16x8*)(sm + RK_O + (16 * (ktb + j) + lr) * 40 + 8 * lg);
        acc_s[j] = MF(qh, kv, acc_s[j]);
        acc_s[j] = MF(ql, kv, acc_s[j]);
      }
    }
  }

  __syncthreads();
#pragma unroll
  for (int j = 0; j < 5; j++)
#pragma unroll
    for (int r = 0; r < 4; r++) {
      int row = 16 * qt + 4 * lg + r;
      int col = 16 * (ktb + j) + lr;
      smf[row * 172 + col] = acc_s[j][r];
    }
  __syncthreads();

  {
    const int row = tid >> 3, l8 = tid & 7;
    int clo = row;          { int t2 = 64 - q0;            if (t2 > clo) clo = t2; }
    int chi = row + 128;    { int t2 = 2047 + 64 - q0;     if (t2 < chi) chi = t2; }
    float m = -1e30f;
    for (int c = l8; c < 160; c += 8)
      if (c >= clo && c <= chi) m = fmaxf(m, smf[row * 172 + c]);
    m = fmaxf(m, __shfl_xor(m, 1));
    m = fmaxf(m, __shfl_xor(m, 2));
    m = fmaxf(m, __shfl_xor(m, 4));
    float ssum = 0.f;
    for (int c = l8; c < 160; c += 8) {
      float e = (c >= clo && c <= chi) ? __expf(smf[row * 172 + c] - m) : 0.f;
      smf[row * 172 + c] = e;
      ssum += e;
    }
    ssum += __shfl_xor(ssum, 1);
    ssum += __shfl_xor(ssum, 2);
    ssum += __shfl_xor(ssum, 4);
    float rinv = 1.f / ssum;
    for (int c = l8; c < 160; c += 8)
      sm[PBF_O + row * 168 + c] = f2bf(smf[row * 172 + c] * rinv);
  }
  __syncthreads();

  const int dtl = (w & 1) * 2;
  bf16x8 pa[5];
#pragma unroll
  for (int ks = 0; ks < 5; ks++)
    pa[ks] = *(const bf16x8*)(sm + PBF_O + (16 * qt + lr) * 168 + 32 * ks + 8 * lg);

  for (int dc = 0; dc < 16; dc++) {
    const int d0 = dc * 64;
    uint4 vr[5];
#pragma unroll
    for (int i = 0; i < 5; i++) {
      int slot = i * 256 + tid;
      int k = slot >> 3, g = slot & 7;
      int kk = q0 - 64 + k;
      kk = kk < 0 ? 0 : (kk > 2047 ? 2047 : kk);
      vr[i] = *(const uint4*)(reprB + baseR + (size_t)kk * 1024 + d0 + 8 * g);
    }
    __syncthreads();
#pragma unroll
    for (int i = 0; i < 5; i++) {
      int slot = i * 256 + tid;
      int k = slot >> 3, g = slot & 7;
      const unsigned short* pv = (const unsigned short*)&vr[i];
#pragma unroll
      for (int j2 = 0; j2 < 8; j2++)
        sm[VT_O + (8 * g + j2) * 168 + k] = pv[j2];
    }
    __syncthreads();
    f32x4 ra0 = (f32x4){0.f, 0.f, 0.f, 0.f};
    f32x4 ra1 = (f32x4){0.f, 0.f, 0.f, 0.f};
#pragma unroll
    for (int ks = 0; ks < 5; ks++) {
      bf16x8 v0 = *(const bf16x8*)(sm + VT_O + (16 * dtl + lr) * 168 + 32 * ks + 8 * lg);
      bf16x8 v1 = *(const bf16x8*)(sm + VT_O + (16 * (dtl + 1) + lr) * 168 + 32 * ks + 8 * lg);
      ra0 = MF(pa[ks], v0, ra0);
      ra1 = MF(pa[ks], v1, ra1);
    }
#pragma unroll
    for (int r = 0; r < 4; r++) {
      int qg = q0 + 16 * qt + 4 * lg + r;
      size_t base = baseR + (size_t)qg * 1024 + d0;
      int dg0 = 16 * dtl + lr, dg1 = 16 * (dtl + 1) + lr;
      float o0 = bfu(reprB[base + dg0]) + fmaxf(ra0[r], 0.f);
      float o1 = bfu(reprB[base + dg1]) + fmaxf(ra1[r], 0.f);
      outB[base + dg0] = f2bf(o0);
      outB[base + dg1] = f2bf(o1);
    }
  }
}

// ---------------------------------------------------------------------------
// fp32-data MFMA kernel. R4 changes:
//  * T14 software pipelining: every staging loop reordered to
//      [bar][write s][bar][issue loads s+1][compute s]
//    so global-load latency hides under the MFMA compute of the previous
//    stage instead of sitting exposed at the vmcnt before ds_write.
//  * V-transpose XOR swizzle: VT pitch 168->192 ushorts, granule index
//    (k>>3) ^ ((row>>2)&7). Breaks the 8-16-way scatter-write conflict
//    (row stride 336B put all lanes on ~2 banks) down to ~4-way; reads
//    stay 16B-aligned and uniformly rotated.
//
// LDS layout (ushort units), phase-disjoint aliasing:
//  Phase A d-loop: WTSH [128][72] @0, WTSL @9216, RQSH [32][72] @18432,
//                  RQSL @20736
//  Phase A3:       RKH [160][40] @0 (aliases WTS), RKL @6400
//  persistent A:   QHI [32][136] @23040, QLO @27392
//  Phase B:        Sls f32 [32][172] @byte0 (aliases WTS/RK, dead),
//                  PBF [32][168] @11008,
//                  VT [64][192] @16384 (swizzled; aliases QHI/QLO, dead;
//                                       ends at 28672 < 31744)
// Total 31744 ushorts = 63488 B -> 2 blocks/CU.
// ---------------------------------------------------------------------------
#define FWTSH_O 0
#define FWTSL_O 9216
#define FRQSH_O 18432
#define FRQSL_O 20736
#define FRKH_O  0
#define FRKL_O  6400
#define FQHI_O  23040
#define FQLO_O  27392
#define FPBF_O  11008
#define FVT_O   16384
#define FVTP    192
#define FSMEMU  31744

// Swizzled VT index: row in [0,64), k in [0,160). 16B-granule XOR keeps
// bf16x8 reads aligned; (row>>2)&7 varies per-lane in the scatter write.
__device__ __forceinline__ int vtidx(int row, int k) {
  return FVT_O + row * FVTP + (((((k >> 3) ^ ((row >> 2) & 7))) << 3) | (k & 7));
}

__global__ void __launch_bounds__(256, 2) attn_mfma_f32(
    const float* __restrict__ reprF,
    const unsigned short* __restrict__ WtH,
    const unsigned short* __restrict__ WtL,
    float* __restrict__ outF) {
  if (data_is_bf16((const unsigned short*)reprF)) return;   // bf16 data -> other kernel

  __shared__ alignas(16) unsigned short sm[FSMEMU];
  float* smf = (float*)sm;

  const int tid = threadIdx.x;
  const int w = tid >> 6, l = tid & 63, lr = l & 15, lg = l >> 4;
  const int b = blockIdx.y, q0 = blockIdx.x * 32;
  const size_t baseR = (size_t)b * 2048 * 1024;
  const int qt = w >> 1;           // q-tile (0/1) this wave owns for S/PV
  const int ktb = (w & 1) * 5;     // S key-tile base

  // staging-thread decompositions (loop-invariant)
  const int wrow = tid >> 3, wc8 = tid & 7;          // Wt: 32 rows/step, 8x16B
  const int rrow = tid >> 4, rcf = tid & 15;         // RQ: 16 rows/step, 16x16B
  const int krow = tid >> 3, kcf = tid & 7;          // RK: 32 rows/step, 8x16B

  f32x4 acc_s[5];
#pragma unroll
  for (int j = 0; j < 5; j++) acc_s[j] = (f32x4){0.f, 0.f, 0.f, 0.f};

  // ---------------- Phase A: Q = R@Wt^T (hi/lo 3-term) + S accumulate ------
  for (int ec = 0; ec < 8; ec++) {
    const int e0 = ec * 128;
    f32x4 acc_q[2][2];
#pragma unroll
    for (int i = 0; i < 2; i++)
#pragma unroll
      for (int j = 0; j < 2; j++) acc_q[i][j] = (f32x4){0.f, 0.f, 0.f, 0.f};

    uint4 wthr[4], wtlr[4];
    float4 rq4[2];
    // prologue: issue stage-0 loads
#pragma unroll
    for (int i = 0; i < 4; i++) {
      size_t off = (size_t)(e0 + 32 * i + wrow) * 1024 + 8 * wc8;
      wthr[i] = *(const uint4*)(WtH + off);
      wtlr[i] = *(const uint4*)(WtL + off);
    }
#pragma unroll
    for (int i = 0; i < 2; i++)
      rq4[i] = *(const float4*)(reprF + baseR + (size_t)(q0 + 16 * i + rrow) * 1024 + 4 * rcf);

    for (int s = 0; s < 16; s++) {
      __syncthreads();   // previous stage's LDS reads (or prev-ec A3) complete
      // ---- write stage s to LDS (vmcnt wait folded in by compiler)
#pragma unroll
      for (int i = 0; i < 4; i++) {
        int row = 32 * i + wrow;
        *(uint4*)(sm + FWTSH_O + row * 72 + 8 * wc8) = wthr[i];
        *(uint4*)(sm + FWTSL_O + row * 72 + 8 * wc8) = wtlr[i];
      }
#pragma unroll
      for (int i = 0; i < 2; i++) {
        int row = 16 * i + rrow;
        ushort4 h4, l4;
        hilo(rq4[i].x, h4.x, l4.x); hilo(rq4[i].y, h4.y, l4.y);
        hilo(rq4[i].z, h4.z, l4.z); hilo(rq4[i].w, h4.w, l4.w);
        *(ushort4*)(sm + FRQSH_O + row * 72 + 4 * rcf) = h4;
        *(ushort4*)(sm + FRQSL_O + row * 72 + 4 * rcf) = l4;
      }
      __syncthreads();   // writes visible
      // ---- issue stage s+1 loads (latency hides under MFMAs below)
      if (s < 15) {
        const int d0n = (s + 1) * 64;
#pragma unroll
        for (int i = 0; i < 4; i++) {
          size_t off = (size_t)(e0 + 32 * i + wrow) * 1024 + d0n + 8 * wc8;
          wthr[i] = *(const uint4*)(WtH + off);
          wtlr[i] = *(const uint4*)(WtL + off);
        }
#pragma unroll
        for (int i = 0; i < 2; i++)
          rq4[i] = *(const float4*)(reprF + baseR + (size_t)(q0 + 16 * i + rrow) * 1024 + d0n + 4 * rcf);
      }
      // ---- compute stage s
#pragma unroll
      for (int h = 0; h < 2; h++) {
        bf16x8 ah0 = *(const bf16x8*)(sm + FRQSH_O + (lr) * 72 + 32 * h + 8 * lg);
        bf16x8 ah1 = *(const bf16x8*)(sm + FRQSH_O + (16 + lr) * 72 + 32 * h + 8 * lg);
        bf16x8 al0 = *(const bf16x8*)(sm + FRQSL_O + (lr) * 72 + 32 * h + 8 * lg);
        bf16x8 al1 = *(const bf16x8*)(sm + FRQSL_O + (16 + lr) * 72 + 32 * h + 8 * lg);
        bf16x8 bh0 = *(const bf16x8*)(sm + FWTSH_O + (32 * w + lr) * 72 + 32 * h + 8 * lg);
        bf16x8 bh1 = *(const bf16x8*)(sm + FWTSH_O + (32 * w + 16 + lr) * 72 + 32 * h + 8 * lg);
        bf16x8 bl0 = *(const bf16x8*)(sm + FWTSL_O + (32 * w + lr) * 72 + 32 * h + 8 * lg);
        bf16x8 bl1 = *(const bf16x8*)(sm + FWTSL_O + (32 * w + 16 + lr) * 72 + 32 * h + 8 * lg);
        acc_q[0][0] = MF(ah0, bh0, acc_q[0][0]);
        acc_q[0][1] = MF(ah0, bh1, acc_q[0][1]);
        acc_q[1][0] = MF(ah1, bh0, acc_q[1][0]);
        acc_q[1][1] = MF(ah1, bh1, acc_q[1][1]);
        acc_q[0][0] = MF(ah0, bl0, acc_q[0][0]);
        acc_q[0][1] = MF(ah0, bl1, acc_q[0][1]);
        acc_q[1][0] = MF(ah1, bl0, acc_q[1][0]);
        acc_q[1][1] = MF(ah1, bl1, acc_q[1][1]);
        acc_q[0][0] = MF(al0, bh0, acc_q[0][0]);
        acc_q[0][1] = MF(al0, bh1, acc_q[0][1]);
        acc_q[1][0] = MF(al1, bh0, acc_q[1][0]);
        acc_q[1][1] = MF(al1, bh1, acc_q[1][1]);
      }
    }

    // issue RK loads for es=0 before the A2 VALU pass (latency hides under it)
    float4 rk4[5];
#pragma unroll
    for (int i = 0; i < 5; i++) {
      int slot = i * 256 + tid;
      int row = slot >> 3;
      int kk = q0 - 64 + row;
      kk = kk < 0 ? 0 : (kk > 2047 ? 2047 : kk);
      rk4[i] = *(const float4*)(reprF + baseR + (size_t)kk * 1024 + e0 + 4 * (slot & 7));
    }

    // A2: Q accumulators -> QHI/QLO (hi/lo bf16 split)
#pragma unroll
    for (int qq = 0; qq < 2; qq++)
#pragma unroll
      for (int et = 0; et < 2; et++)
#pragma unroll
        for (int r = 0; r < 4; r++) {
          int row = 16 * qq + 4 * lg + r;
          int col = 32 * w + 16 * et + lr;
          float v = acc_q[qq][et][r];
          unsigned short hi, lo;
          hilo(v, hi, lo);
          sm[FQHI_O + row * 136 + col] = hi;
          sm[FQLO_O + row * 136 + col] = lo;
        }

    // A3: S += Qchunk @ K^T (hi/lo 3-term), 4 e-slices of 32, pipelined
    for (int es = 0; es < 4; es++) {
      __syncthreads();   // d-loop compute (es==0: WTS alias) / prev RK reads + A2 writes
#pragma unroll
      for (int i = 0; i < 5; i++) {
        int slot = i * 256 + tid;
        int row = slot >> 3, cf = slot & 7;
        ushort4 h4, l4;
        hilo(rk4[i].x, h4.x, l4.x); hilo(rk4[i].y, h4.y, l4.y);
        hilo(rk4[i].z, h4.z, l4.z); hilo(rk4[i].w, h4.w, l4.w);
        *(ushort4*)(sm + FRKH_O + row * 40 + 4 * cf) = h4;
        *(ushort4*)(sm + FRKL_O + row * 40 + 4 * cf) = l4;
      }
      __syncthreads();
      if (es < 3) {
#pragma unroll
        for (int i = 0; i < 5; i++) {
          int slot = i * 256 + tid;
          int row = slot >> 3;
          int kk = q0 - 64 + row;
          kk = kk < 0 ? 0 : (kk > 2047 ? 2047 : kk);
          rk4[i] = *(const float4*)(reprF + baseR + (size_t)kk * 1024 + e0 + 32 * (es + 1) + 4 * (slot & 7));
        }
      }
      bf16x8 qh = *(const bf16x8*)(sm + FQHI_O + (16 * qt + lr) * 136 + 32 * es + 8 * lg);
      bf16x8 ql = *(const bf16x8*)(sm + FQLO_O + (16 * qt + lr) * 136 + 32 * es + 8 * lg);
#pragma unroll
      for (int j = 0; j < 5; j++) {
        bf16x8 kh = *(const bf16x8*)(sm + FRKH_O + (16 * (ktb + j) + lr) * 40 + 8 * lg);
        bf16x8 kl = *(const bf16x8*)(sm + FRKL_O + (16 * (ktb + j) + lr) * 40 + 8 * lg);
        acc_s[j] = MF(qh, kh, acc_s[j]);
        acc_s[j] = MF(qh, kl, acc_s[j]);
        acc_s[j] = MF(ql, kh, acc_s[j]);
      }
    }
  }

  __syncthreads();
  // scores -> Sls (f32, pitch 172) @0 (WTS/RK dead)
#pragma unroll
  for (int j = 0; j < 5; j++)
#pragma unroll
    for (int r = 0; r < 4; r++) {
      int row = 16 * qt + 4 * lg + r;
      int col = 16 * (ktb + j) + lr;
      smf[row * 172 + col] = acc_s[j][r];
    }
  __syncthreads();

  // masked softmax (8 lanes/row), probs -> PBF bf16
  {
    const int row = tid >> 3, l8 = tid & 7;
    int clo = row;          { int t2 = 64 - q0;            if (t2 > clo) clo = t2; }
    int chi = row + 128;    { int t2 = 2047 + 64 - q0;     if (t2 < chi) chi = t2; }
    float m = -1e30f;
    for (int c = l8; c < 160; c += 8)
      if (c >= clo && c <= chi) m = fmaxf(m, smf[row * 172 + c]);
    m = fmaxf(m, __shfl_xor(m, 1));
    m = fmaxf(m, __shfl_xor(m, 2));
    m = fmaxf(m, __shfl_xor(m, 4));
    float ssum = 0.f;
    for (int c = l8; c < 160; c += 8) {
      float e = (c >= clo && c <= chi) ? __expf(smf[row * 172 + c] - m) : 0.f;
      smf[row * 172 + c] = e;
      ssum += e;
    }
    ssum += __shfl_xor(ssum, 1);
    ssum += __shfl_xor(ssum, 2);
    ssum += __shfl_xor(ssum, 4);
    float rinv = 1.f / ssum;
    for (int c = l8; c < 160; c += 8)
      sm[FPBF_O + row * 168 + c] = f2bf(smf[row * 172 + c] * rinv);
  }
  __syncthreads();

  // ---------------- Phase B: ra = P @ V (single-bf16), out = repr+relu -----
  const int dtl = (w & 1) * 2;
  bf16x8 pa[5];
#pragma unroll
  for (int ks = 0; ks < 5; ks++)
    pa[ks] = *(const bf16x8*)(sm + FPBF_O + (16 * qt + lr) * 168 + 32 * ks + 8 * lg);

  float4 vr4[10];
  // prologue: issue dc=0 V loads
#pragma unroll
  for (int i = 0; i < 10; i++) {
    int slot = i * 256 + tid;
    int k = slot >> 4, g = slot & 15;
    int kk = q0 - 64 + k;
    kk = kk < 0 ? 0 : (kk > 2047 ? 2047 : kk);
    vr4[i] = *(const float4*)(reprF + baseR + (size_t)kk * 1024 + 4 * g);
  }

  for (int dc = 0; dc < 16; dc++) {
    const int d0 = dc * 64;
    __syncthreads();   // previous chunk's VT reads done (dc=0: QHI/QLO dead)
#pragma unroll
    for (int i = 0; i < 10; i++) {
      int slot = i * 256 + tid;
      int k = slot >> 4, g = slot & 15;
      sm[vtidx(4 * g + 0, k)] = f2bf(vr4[i].x);
      sm[vtidx(4 * g + 1, k)] = f2bf(vr4[i].y);
      sm[vtidx(4 * g + 2, k)] = f2bf(vr4[i].z);
      sm[vtidx(4 * g + 3, k)] = f2bf(vr4[i].w);
    }
    __syncthreads();
    if (dc < 15) {
      const int d0n = d0 + 64;
#pragma unroll
      for (int i = 0; i < 10; i++) {
        int slot = i * 256 + tid;
        int k = slot >> 4, g = slot & 15;
        int kk = q0 - 64 + k;
        kk = kk < 0 ? 0 : (kk > 2047 ? 2047 : kk);
        vr4[i] = *(const float4*)(reprF + baseR + (size_t)kk * 1024 + d0n + 4 * g);
      }
    }
    f32x4 ra0 = (f32x4){0.f, 0.f, 0.f, 0.f};
    f32x4 ra1 = (f32x4){0.f, 0.f, 0.f, 0.f};
    const int row0 = 16 * dtl + lr, row1 = 16 * (dtl + 1) + lr;
#pragma unroll
    for (int ks = 0; ks < 5; ks++) {
      bf16x8 v0 = *(const bf16x8*)(sm + vtidx(row0, 32 * ks + 8 * lg));
      bf16x8 v1 = *(const bf16x8*)(sm + vtidx(row1, 32 * ks + 8 * lg));
      ra0 = MF(pa[ks], v0, ra0);
      ra1 = MF(pa[ks], v1, ra1);
    }
#pragma unroll
    for (int r = 0; r < 4; r++) {
      int qg = q0 + 16 * qt + 4 * lg + r;
      size_t base = baseR + (size_t)qg * 1024 + d0;
      int dg0 = 16 * dtl + lr, dg1 = 16 * (dtl + 1) + lr;
      outF[base + dg0] = reprF[base + dg0] + fmaxf(ra0[r], 0.f);
      outF[base + dg1] = reprF[base + dg1] + fmaxf(ra1[r], 0.f);
    }
  }
}

extern "C" void kernel_launch(void* const* d_in, const int* in_sizes, int n_in,
                              void* d_out, int out_size, void* d_ws, size_t ws_size,
                              hipStream_t stream) {
  const void* repr = d_in[0];
  const void* W    = d_in[1];
  dim3 grid(SEQL / QT, NB);   // (64, 8) = 512 blocks

  const bool use_mfma = (d_ws != nullptr) && (ws_size >= (size_t)4 * 1024 * 1024);
  if (use_mfma) {
    tposeW2<<<dim3(256), dim3(256), 0, stream>>>(repr, W, d_ws);
    attn_mfma<<<grid, dim3(256), 0, stream>>>(
        (const unsigned short*)repr, (const unsigned short*)d_ws, (unsigned short*)d_out);
    attn_mfma_f32<<<grid, dim3(256), 0, stream>>>(
        (const float*)repr, (const unsigned short*)d_ws,
        (const unsigned short*)d_ws + (1u << 20), (float*)d_out);
  } else {
    attn_fused<true><<<grid, dim3(256), 0, stream>>>(repr, W, d_out);
    attn_fused<false><<<grid, dim3(256), 0, stream>>>(repr, W, d_out);
  }
}

// Round 5
// 341.771 us; speedup vs baseline: 3.7587x; 1.6286x over previous
//
#include <hip/hip_runtime.h>

// AttentionWindow: out = repr + relu(softmax_masked((repr@W)@repr^T) @ repr)
// BATCH=8, SEQ=2048, HIDDEN=1024, window half-width 64 (|i-j|>64 masked).
//
// Modes (uniform data sniff):
//   bf16 data  -> attn_mfma      (verified; unchanged)
//   fp32 data  -> attn_mfma_f32  (R5: Wt in fragment-order workspace ->
//                                 B-operands load global->register directly,
//                                 no LDS staging for Wt; RQ LDS double-buffer
//                                 -> 1 barrier/stage; fixed VT swizzle)
//   no workspace -> proven VALU pair.

#define SEQL 2048
#define HID  1024
#define NB   8
#define QT   32
#define KT   160
#define DCO  128
#define EC   32
#define DS   32
#define RP   36
#define WP   132
#define QP   132
#define KP   36
#define SP   161

#define RS_OFF  0
#define WS_OFF  1152
#define KS_OFF  0
#define QCS_OFF 5760
#define SC_OFF  5760
#define SMEM_F  10912

__device__ __forceinline__ float bfu(unsigned int lo16) {
  union { unsigned int i; float f; } v; v.i = lo16 << 16; return v.f;
}
__device__ __forceinline__ unsigned short f2bf(float f) {
  union { float f; unsigned int i; } v; v.f = f;
  unsigned int r = v.i + 0x7FFFu + ((v.i >> 16) & 1u);   // RNE
  return (unsigned short)(r >> 16);
}
__device__ __forceinline__ void hilo(float v, unsigned short& h, unsigned short& l) {
  h = f2bf(v);
  l = f2bf(v - bfu(h));
}

// Uniform dtype sniff (thread-invariant).
__device__ bool data_is_bf16(const unsigned short* u) {
  int cnt = 0;
  for (int i = 0; i < 256; i++) {
    int e = (u[i] >> 7) & 0xFF;
    if (e >= 107 && e <= 131) cnt++;
  }
  return cnt >= 230;
}

template<bool BF16>
__device__ __forceinline__ float4 ld4(const void* p, size_t idx) {
  if (BF16) {
    uint2 u = *(const uint2*)((const unsigned short*)p + idx);
    float4 r;
    r.x = bfu(u.x & 0xFFFFu); r.y = bfu(u.x >> 16);
    r.z = bfu(u.y & 0xFFFFu); r.w = bfu(u.y >> 16);
    return r;
  } else {
    return *(const float4*)((const float*)p + idx);
  }
}

template<bool BF16>
__device__ __forceinline__ void st4(void* p, size_t idx, float4 v) {
  if (BF16) {
    ushort4 o;
    o.x = f2bf(v.x); o.y = f2bf(v.y); o.z = f2bf(v.z); o.w = f2bf(v.w);
    *(ushort4*)((unsigned short*)p + idx) = o;
  } else {
    *(float4*)((float*)p + idx) = v;
  }
}

__device__ __forceinline__ void fma4(float4& q, float a, const float4& w) {
  q.x += a * w.x; q.y += a * w.y; q.z += a * w.z; q.w += a * w.w;
}

// ---------------------------------------------------------------------------
// OLD proven VALU kernel (fallback when no workspace)
// ---------------------------------------------------------------------------
template<bool BF16>
__global__ void __launch_bounds__(256) attn_fused(
    const void* __restrict__ reprv, const void* __restrict__ Wv,
    void* __restrict__ outv) {
  if (data_is_bf16((const unsigned short*)reprv) != BF16) return;

  __shared__ float smem[SMEM_F];
  const int tid = threadIdx.x;
  const int b = blockIdx.y;
  const int q0 = blockIdx.x * QT;
  const size_t baseR = (size_t)b * SEQL * HID;

  const int tx = tid & 31, ty = tid >> 5;

  float acc[4][5];
#pragma unroll
  for (int i = 0; i < 4; i++)
#pragma unroll
    for (int j = 0; j < 5; j++) acc[i][j] = 0.f;

  for (int d0 = 0; d0 < HID; d0 += DCO) {
    float4 qc[4];
#pragma unroll
    for (int i = 0; i < 4; i++) qc[i] = make_float4(0.f, 0.f, 0.f, 0.f);

    for (int e0 = 0; e0 < HID; e0 += EC) {
      {
        int row = tid >> 3, cg = tid & 7;
        float4 v = ld4<BF16>(reprv, baseR + (size_t)(q0 + row) * HID + e0 + 4 * cg);
        *(float4*)&smem[RS_OFF + row * RP + 4 * cg] = v;
      }
#pragma unroll
      for (int i2 = 0; i2 < 4; i2++) {
        int f = i2 * 256 + tid;
        int row = f >> 5, cg = f & 31;
        float4 v = ld4<BF16>(Wv, (size_t)(e0 + row) * HID + d0 + 4 * cg);
        *(float4*)&smem[WS_OFF + row * WP + 4 * cg] = v;
      }
      __syncthreads();
#pragma unroll
      for (int ee = 0; ee < EC; ee += 4) {
        float4 rv[4];
#pragma unroll
        for (int i = 0; i < 4; i++)
          rv[i] = *(const float4*)&smem[RS_OFF + (ty + 8 * i) * RP + ee];
        {
          float4 wv = *(const float4*)&smem[WS_OFF + (ee + 0) * WP + 4 * tx];
          fma4(qc[0], rv[0].x, wv); fma4(qc[1], rv[1].x, wv);
          fma4(qc[2], rv[2].x, wv); fma4(qc[3], rv[3].x, wv);
        }
        {
          float4 wv = *(const float4*)&smem[WS_OFF + (ee + 1) * WP + 4 * tx];
          fma4(qc[0], rv[0].y, wv); fma4(qc[1], rv[1].y, wv);
          fma4(qc[2], rv[2].y, wv); fma4(qc[3], rv[3].y, wv);
        }
        {
          float4 wv = *(const float4*)&smem[WS_OFF + (ee + 2) * WP + 4 * tx];
          fma4(qc[0], rv[0].z, wv); fma4(qc[1], rv[1].z, wv);
          fma4(qc[2], rv[2].z, wv); fma4(qc[3], rv[3].z, wv);
        }
        {
          float4 wv = *(const float4*)&smem[WS_OFF + (ee + 3) * WP + 4 * tx];
          fma4(qc[0], rv[0].w, wv); fma4(qc[1], rv[1].w, wv);
          fma4(qc[2], rv[2].w, wv); fma4(qc[3], rv[3].w, wv);
        }
      }
      __syncthreads();
    }

#pragma unroll
    for (int i = 0; i < 4; i++)
      *(float4*)&smem[QCS_OFF + (ty + 8 * i) * QP + 4 * tx] = qc[i];

    for (int s = 0; s < DCO; s += DS) {
#pragma unroll
      for (int i2 = 0; i2 < 5; i2++) {
        int f = i2 * 256 + tid;
        int row = f >> 3, cg = f & 7;
        int kk = q0 - 64 + row;
        kk = kk < 0 ? 0 : (kk > SEQL - 1 ? SEQL - 1 : kk);
        float4 v = ld4<BF16>(reprv, baseR + (size_t)kk * HID + d0 + s + 4 * cg);
        *(float4*)&smem[KS_OFF + row * KP + 4 * cg] = v;
      }
      __syncthreads();
#pragma unroll
      for (int dd = 0; dd < DS; dd += 4) {
        float4 qv[4];
#pragma unroll
        for (int i = 0; i < 4; i++)
          qv[i] = *(const float4*)&smem[QCS_OFF + (ty + 8 * i) * QP + s + dd];
#pragma unroll
        for (int j = 0; j < 5; j++) {
          float4 kv = *(const float4*)&smem[KS_OFF + (tx + 32 * j) * KP + dd];
#pragma unroll
          for (int i = 0; i < 4; i++)
            acc[i][j] += qv[i].x * kv.x + qv[i].y * kv.y + qv[i].z * kv.z + qv[i].w * kv.w;
        }
      }
      __syncthreads();
    }
  }

#pragma unroll
  for (int i = 0; i < 4; i++)
#pragma unroll
    for (int j = 0; j < 5; j++)
      smem[SC_OFF + (ty + 8 * i) * SP + tx + 32 * j] = acc[i][j];
  __syncthreads();

  {
    const int row = tid >> 3, l8 = tid & 7;
    int clo = row;          { int t = 64 - q0;            if (t > clo) clo = t; }
    int chi = row + 128;    { int t = SEQL - 1 + 64 - q0; if (t < chi) chi = t; }
    float m = -1e30f;
    for (int c = l8; c < KT; c += 8)
      if (c >= clo && c <= chi) m = fmaxf(m, smem[SC_OFF + row * SP + c]);
    m = fmaxf(m, __shfl_xor(m, 1));
    m = fmaxf(m, __shfl_xor(m, 2));
    m = fmaxf(m, __shfl_xor(m, 4));
    float ssum = 0.f;
    for (int c = l8; c < KT; c += 8) {
      float e = (c >= clo && c <= chi) ? __expf(smem[SC_OFF + row * SP + c] - m) : 0.f;
      smem[SC_OFF + row * SP + c] = e;
      ssum += e;
    }
    ssum += __shfl_xor(ssum, 1);
    ssum += __shfl_xor(ssum, 2);
    ssum += __shfl_xor(ssum, 4);
    float rinv = 1.f / ssum;
    for (int c = l8; c < KT; c += 8) smem[SC_OFF + row * SP + c] *= rinv;
  }
  __syncthreads();

  const int rr = tid >> 3, dq = tid & 7;
  for (int d0 = 0; d0 < HID; d0 += DS) {
#pragma unroll
    for (int i2 = 0; i2 < 5; i2++) {
      int f = i2 * 256 + tid;
      int row = f >> 3, cg = f & 7;
      int kk = q0 - 64 + row;
      kk = kk < 0 ? 0 : (kk > SEQL - 1 ? SEQL - 1 : kk);
      float4 v = ld4<BF16>(reprv, baseR + (size_t)kk * HID + d0 + 4 * cg);
      *(float4*)&smem[KS_OFF + row * KP + 4 * cg] = v;
    }
    __syncthreads();
    float4 o = make_float4(0.f, 0.f, 0.f, 0.f);
#pragma unroll 4
    for (int c = 0; c < KT; c++) {
      float4 kv = *(const float4*)&smem[KS_OFF + c * KP + 4 * dq];
      float p = smem[SC_OFF + rr * SP + c];
      o.x += p * kv.x; o.y += p * kv.y; o.z += p * kv.z; o.w += p * kv.w;
    }
    size_t goff = baseR + (size_t)(q0 + rr) * HID + d0 + 4 * dq;
    float4 rv = ld4<BF16>(reprv, goff);
    float4 ov;
    ov.x = rv.x + fmaxf(o.x, 0.f);
    ov.y = rv.y + fmaxf(o.y, 0.f);
    ov.z = rv.z + fmaxf(o.z, 0.f);
    ov.w = rv.w + fmaxf(o.w, 0.f);
    st4<BF16>(outv, goff, ov);
    __syncthreads();
  }
}

// ---------------------------------------------------------------------------
// MFMA common
// ---------------------------------------------------------------------------
typedef float f32x4 __attribute__((ext_vector_type(4)));
typedef short bf16x8 __attribute__((ext_vector_type(8)));

#define MF(a_, b_, c_) __builtin_amdgcn_mfma_f32_16x16x32_bf16((a_), (b_), (c_), 0, 0, 0)

// W-transpose (dual-mode).
//  bf16 data: Wt bf16 linear [e][d] @ws0 (2MB, exact) — for attn_mfma.
//  fp32 data: FRAGMENT-ordered hi/lo split for direct global->register
//    B-operand loads in attn_mfma_f32:
//    dest_ush(e,d) = (((e>>4)<<5)|(d>>5))*512 + ((((d>>3)&3)<<4)|(e&15))*8 + (d&7)
//    i.e. [R16=e/16][C32=d/32][lane l: lr=e%16, lg=(d/8)%4][j=d%8] —
//    lane l of a wave reads its 16B fragment at frag_base + l*16B (coalesced).
//    WfH @ws0 (2MB), WfL @ws+2MB.
__global__ void __launch_bounds__(256) tposeW2(
    const void* __restrict__ reprv, const void* __restrict__ Wv,
    void* __restrict__ wsv) {
  const bool isbf = data_is_bf16((const unsigned short*)reprv);
  __shared__ alignas(16) unsigned char twsb[64 * 68 * 4];
  const int t = threadIdx.x;
  const int d0 = (blockIdx.x & 15) * 64, e0 = (blockIdx.x >> 4) * 64;
  if (isbf) {
    unsigned short* tl = (unsigned short*)twsb;
    const unsigned short* WB = (const unsigned short*)Wv;
    unsigned short* WtB = (unsigned short*)wsv;
#pragma unroll
    for (int i = 0; i < 2; i++) {
      int slot = i * 256 + t, row = slot >> 3, c8 = slot & 7;
      *(uint4*)(tl + row * 72 + 8 * c8) =
          *(const uint4*)(WB + (size_t)(d0 + row) * 1024 + e0 + 8 * c8);
    }
    __syncthreads();
#pragma unroll
    for (int i = 0; i < 2; i++) {
      int slot = i * 256 + t, er = slot >> 3, c8 = slot & 7;
      unsigned short v[8];
#pragma unroll
      for (int j = 0; j < 8; j++) v[j] = tl[(8 * c8 + j) * 72 + er];
      *(uint4*)(WtB + (size_t)(e0 + er) * 1024 + d0 + 8 * c8) = *(const uint4*)v;
    }
  } else {
    float* tlf = (float*)twsb;
    const float* WF = (const float*)Wv;
    unsigned short* WfH = (unsigned short*)wsv;
    unsigned short* WfL = WfH + (1u << 20);   // +2 MB
#pragma unroll
    for (int i = 0; i < 4; i++) {
      int slot = i * 256 + t, row = slot >> 4, cf = slot & 15;
      *(float4*)&tlf[row * 68 + 4 * cf] =
          *(const float4*)(WF + (size_t)(d0 + row) * 1024 + e0 + 4 * cf);
    }
    __syncthreads();
#pragma unroll
    for (int i = 0; i < 2; i++) {
      int slot = i * 256 + t, er = slot >> 3, c8 = slot & 7;
      int e = e0 + er;
      int dg = d0 + 8 * c8;
      unsigned short vh[8], vl[8];
#pragma unroll
      for (int j = 0; j < 8; j++) {
        float v = tlf[(8 * c8 + j) * 68 + er];
        hilo(v, vh[j], vl[j]);
      }
      size_t dst = (size_t)(((e >> 4) << 5) | (dg >> 5)) * 512
                 + (size_t)(((((dg >> 3) & 3) << 4) | (e & 15))) * 8;
      *(uint4*)(WfH + dst) = *(const uint4*)vh;
      *(uint4*)(WfL + dst) = *(const uint4*)vl;
    }
  }
}

// ---------------------------------------------------------------------------
// bf16-data MFMA kernel (round-1 verified, unchanged)
// ---------------------------------------------------------------------------
#define WTS_O 0
#define RQS_O 9216
#define RK_O  11520
#define QHI_O 17920
#define QLO_O 22272
#define PBF_O 11008
#define VT_O  16384
#define SMEMU 27136

__global__ void __launch_bounds__(256, 2) attn_mfma(
    const unsigned short* __restrict__ reprB,
    const unsigned short* __restrict__ WtB,
    unsigned short* __restrict__ outB) {
  if (!data_is_bf16(reprB)) return;

  __shared__ alignas(16) unsigned short sm[SMEMU];
  float* smf = (float*)sm;

  const int tid = threadIdx.x;
  const int w = tid >> 6, l = tid & 63, lr = l & 15, lg = l >> 4;
  const int b = blockIdx.y, q0 = blockIdx.x * 32;
  const size_t baseR = (size_t)b * 2048 * 1024;
  const int qt = w >> 1;
  const int ktb = (w & 1) * 5;

  f32x4 acc_s[5];
#pragma unroll
  for (int j = 0; j < 5; j++) acc_s[j] = (f32x4){0.f, 0.f, 0.f, 0.f};

  for (int ec = 0; ec < 8; ec++) {
    const int e0 = ec * 128;
    f32x4 acc_q[2][2];
#pragma unroll
    for (int i = 0; i < 2; i++)
#pragma unroll
      for (int j = 0; j < 2; j++) acc_q[i][j] = (f32x4){0.f, 0.f, 0.f, 0.f};

    for (int s = 0; s < 16; s++) {
      const int d0 = s * 64;
      uint4 wtr[4], rqr;
#pragma unroll
      for (int i = 0; i < 4; i++) {
        int slot = i * 256 + tid, row = slot >> 3, c8 = slot & 7;
        wtr[i] = *(const uint4*)(WtB + (size_t)(e0 + row) * 1024 + d0 + 8 * c8);
      }
      {
        int row = tid >> 3, c8 = tid & 7;
        rqr = *(const uint4*)(reprB + baseR + (size_t)(q0 + row) * 1024 + d0 + 8 * c8);
      }
      __syncthreads();
#pragma unroll
      for (int i = 0; i < 4; i++) {
        int slot = i * 256 + tid, row = slot >> 3, c8 = slot & 7;
        *(uint4*)(sm + WTS_O + row * 72 + 8 * c8) = wtr[i];
      }
      {
        int row = tid >> 3, c8 = tid & 7;
        *(uint4*)(sm + RQS_O + row * 72 + 8 * c8) = rqr;
      }
      __syncthreads();
#pragma unroll
      for (int h = 0; h < 2; h++) {
        bf16x8 a0 = *(const bf16x8*)(sm + RQS_O + (lr) * 72 + 32 * h + 8 * lg);
        bf16x8 a1 = *(const bf16x8*)(sm + RQS_O + (16 + lr) * 72 + 32 * h + 8 * lg);
        bf16x8 b0 = *(const bf16x8*)(sm + WTS_O + (32 * w + lr) * 72 + 32 * h + 8 * lg);
        bf16x8 b1 = *(const bf16x8*)(sm + WTS_O + (32 * w + 16 + lr) * 72 + 32 * h + 8 * lg);
        acc_q[0][0] = MF(a0, b0, acc_q[0][0]);
        acc_q[0][1] = MF(a0, b1, acc_q[0][1]);
        acc_q[1][0] = MF(a1, b0, acc_q[1][0]);
        acc_q[1][1] = MF(a1, b1, acc_q[1][1]);
      }
    }

#pragma unroll
    for (int qq = 0; qq < 2; qq++)
#pragma unroll
      for (int et = 0; et < 2; et++)
#pragma unroll
        for (int r = 0; r < 4; r++) {
          int row = 16 * qq + 4 * lg + r;
          int col = 32 * w + 16 * et + lr;
          float v = acc_q[qq][et][r];
          unsigned short hi = f2bf(v);
          sm[QHI_O + row * 136 + col] = hi;
          sm[QLO_O + row * 136 + col] = f2bf(v - bfu(hi));
        }

    for (int es = 0; es < 4; es++) {
      uint4 rkr[3];
#pragma unroll
      for (int i = 0; i < 3; i++) {
        int slot = i * 256 + tid;
        if (slot < 640) {
          int row = slot >> 2, c8 = slot & 3;
          int kk = q0 - 64 + row;
          kk = kk < 0 ? 0 : (kk > 2047 ? 2047 : kk);
          rkr[i] = *(const uint4*)(reprB + baseR + (size_t)kk * 1024 + e0 + 32 * es + 8 * c8);
        }
      }
      __syncthreads();
#pragma unroll
      for (int i = 0; i < 3; i++) {
        int slot = i * 256 + tid;
        if (slot < 640) {
          int row = slot >> 2, c8 = slot & 3;
          *(uint4*)(sm + RK_O + row * 40 + 8 * c8) = rkr[i];
        }
      }
      __syncthreads();
      bf16x8 qh = *(const bf16x8*)(sm + QHI_O + (16 * qt + lr) * 136 + 32 * es + 8 * lg);
      bf16x8 ql = *(const bf16x8*)(sm + QLO_O + (16 * qt + lr) * 136 + 32 * es + 8 * lg);
#pragma unroll
      for (int j = 0; j < 5; j++) {
        bf16x8 kv = *(const bf16x8*)(sm + RK_O + (16 * (ktb + j) + lr) * 40 + 8 * lg);
        acc_s[j] = MF(qh, kv, acc_s[j]);
        acc_s[j] = MF(ql, kv, acc_s[j]);
      }
    }
  }

  __syncthreads();
#pragma unroll
  for (int j = 0; j < 5; j++)
#pragma unroll
    for (int r = 0; r < 4; r++) {
      int row = 16 * qt + 4 * lg + r;
      int col = 16 * (ktb + j) + lr;
      smf[row * 172 + col] = acc_s[j][r];
    }
  __syncthreads();

  {
    const int row = tid >> 3, l8 = tid & 7;
    int clo = row;          { int t2 = 64 - q0;            if (t2 > clo) clo = t2; }
    int chi = row + 128;    { int t2 = 2047 + 64 - q0;     if (t2 < chi) chi = t2; }
    float m = -1e30f;
    for (int c = l8; c < 160; c += 8)
      if (c >= clo && c <= chi) m = fmaxf(m, smf[row * 172 + c]);
    m = fmaxf(m, __shfl_xor(m, 1));
    m = fmaxf(m, __shfl_xor(m, 2));
    m = fmaxf(m, __shfl_xor(m, 4));
    float ssum = 0.f;
    for (int c = l8; c < 160; c += 8) {
      float e = (c >= clo && c <= chi) ? __expf(smf[row * 172 + c] - m) : 0.f;
      smf[row * 172 + c] = e;
      ssum += e;
    }
    ssum += __shfl_xor(ssum, 1);
    ssum += __shfl_xor(ssum, 2);
    ssum += __shfl_xor(ssum, 4);
    float rinv = 1.f / ssum;
    for (int c = l8; c < 160; c += 8)
      sm[PBF_O + row * 168 + c] = f2bf(smf[row * 172 + c] * rinv);
  }
  __syncthreads();

  const int dtl = (w & 1) * 2;
  bf16x8 pa[5];
#pragma unroll
  for (int ks = 0; ks < 5; ks++)
    pa[ks] = *(const bf16x8*)(sm + PBF_O + (16 * qt + lr) * 168 + 32 * ks + 8 * lg);

  for (int dc = 0; dc < 16; dc++) {
    const int d0 = dc * 64;
    uint4 vr[5];
#pragma unroll
    for (int i = 0; i < 5; i++) {
      int slot = i * 256 + tid;
      int k = slot >> 3, g = slot & 7;
      int kk = q0 - 64 + k;
      kk = kk < 0 ? 0 : (kk > 2047 ? 2047 : kk);
      vr[i] = *(const uint4*)(reprB + baseR + (size_t)kk * 1024 + d0 + 8 * g);
    }
    __syncthreads();
#pragma unroll
    for (int i = 0; i < 5; i++) {
      int slot = i * 256 + tid;
      int k = slot >> 3, g = slot & 7;
      const unsigned short* pv = (const unsigned short*)&vr[i];
#pragma unroll
      for (int j2 = 0; j2 < 8; j2++)
        sm[VT_O + (8 * g + j2) * 168 + k] = pv[j2];
    }
    __syncthreads();
    f32x4 ra0 = (f32x4){0.f, 0.f, 0.f, 0.f};
    f32x4 ra1 = (f32x4){0.f, 0.f, 0.f, 0.f};
#pragma unroll
    for (int ks = 0; ks < 5; ks++) {
      bf16x8 v0 = *(const bf16x8*)(sm + VT_O + (16 * dtl + lr) * 168 + 32 * ks + 8 * lg);
      bf16x8 v1 = *(const bf16x8*)(sm + VT_O + (16 * (dtl + 1) + lr) * 168 + 32 * ks + 8 * lg);
      ra0 = MF(pa[ks], v0, ra0);
      ra1 = MF(pa[ks], v1, ra1);
    }
#pragma unroll
    for (int r = 0; r < 4; r++) {
      int qg = q0 + 16 * qt + 4 * lg + r;
      size_t base = baseR + (size_t)qg * 1024 + d0;
      int dg0 = 16 * dtl + lr, dg1 = 16 * (dtl + 1) + lr;
      float o0 = bfu(reprB[base + dg0]) + fmaxf(ra0[r], 0.f);
      float o1 = bfu(reprB[base + dg1]) + fmaxf(ra1[r], 0.f);
      outB[base + dg0] = f2bf(o0);
      outB[base + dg1] = f2bf(o1);
    }
  }
}

// ---------------------------------------------------------------------------
// fp32-data MFMA kernel, R5.
//  * B-operands (Wt hi/lo) load global->register directly from the
//    fragment-ordered workspace (coalesced 16B/lane), 2-stage register
//    prefetch (Bf[3] rotation, fully unrolled s-loop -> constant indices).
//    No Wt LDS staging at all.
//  * RQ (A-operand) LDS double-buffer -> ONE barrier per d-stage.
//  * VT swizzle fixed: pitch 192, m = (row ^ row>>2) & 7 -> ~2-way writes,
//    uniform reads (previous pitch-192 m=(row>>2)&7 left reads 4-way and
//    writes helped only 16->4-way).
//
// LDS (ush), phase-disjoint aliasing:
//  d-loop:  RQ dbuf: buf0 @0 (H 0..2304, L 2304..4608), buf1 @4608..9216
//  A3:      RKH @0..6400, RKL @6400..12800 (aliases RQ bufs)
//  persist: QHI @12800..17152, QLO @17152..21504
//  epilog:  Sls f32 @byte 0 (ush 0..11008, over RK/RQ dead)
//           VT [64][192] @0..12288 (over Sls dead)
//           PBF [32][168] @12288..17664 (over QHI/QLO dead)
// Total 21504 ush = 43008 B.
// ---------------------------------------------------------------------------
#define FRQB(k)  ((k) * 4608)
#define FRKH_O  0
#define FRKL_O  6400
#define FQHI_O  12800
#define FQLO_O  17152
#define FPBF_O  12288
#define FVT_O   0
#define FSMEMU  21504

// Swizzled VT index: row in [0,64), k in [0,160). 16B-granule XOR; m mixes
// low row bits (read-spread across lr) and row>>2 (write-spread across g).
__device__ __forceinline__ int vtidx(int row, int k) {
  int m = (row ^ (row >> 2)) & 7;
  return FVT_O + row * 192 + ((((k >> 3) ^ m) << 3) | (k & 7));
}

__global__ void __launch_bounds__(256, 2) attn_mfma_f32(
    const float* __restrict__ reprF,
    const unsigned short* __restrict__ WfH,
    const unsigned short* __restrict__ WfL,
    float* __restrict__ outF) {
  if (data_is_bf16((const unsigned short*)reprF)) return;   // bf16 data -> other kernel

  __shared__ alignas(16) unsigned short sm[FSMEMU];
  float* smf = (float*)sm;

  const int tid = threadIdx.x;
  const int w = tid >> 6, l = tid & 63, lr = l & 15, lg = l >> 4;
  const int b = blockIdx.y, q0 = blockIdx.x * 32;
  const size_t baseR = (size_t)b * 2048 * 1024;
  const int qt = w >> 1;           // q-tile (0/1) this wave owns for S/PV
  const int ktb = (w & 1) * 5;     // S key-tile base

  const int rrow = tid >> 4, rcf = tid & 15;   // RQ staging: 16 rows x 16x16B

  f32x4 acc_s[5];
#pragma unroll
  for (int j = 0; j < 5; j++) acc_s[j] = (f32x4){0.f, 0.f, 0.f, 0.f};

  // ---------------- Phase A: Q = R@Wt (hi/lo 3-term) + S accumulate --------
  for (int ec = 0; ec < 8; ec++) {
    const int e0 = ec * 128;
    const int ecw8 = 8 * ec + 2 * w;   // R16 base for this wave's B-frags
    f32x4 acc_q[2][2];
#pragma unroll
    for (int i = 0; i < 2; i++)
#pragma unroll
      for (int j = 0; j < 2; j++) acc_q[i][j] = (f32x4){0.f, 0.f, 0.f, 0.f};

    bf16x8 Bf[3][8];     // [rotation][2*bt+h (hi) | 4+2*bt+h (lo)]
    float4 rqv[2][2];    // [stage&1][i] — Q-rows fp32 in flight

    // B-frag load: buffer bidx <- stage sidx (all indices compile-time const)
#define LDB(bidx, sidx) {                                                      \
    size_t f00 = ((size_t)((((ecw8 + 0) << 5) + 2 * (sidx) + 0)) << 9) + l * 8;\
    size_t f01 = ((size_t)((((ecw8 + 0) << 5) + 2 * (sidx) + 1)) << 9) + l * 8;\
    size_t f10 = ((size_t)((((ecw8 + 1) << 5) + 2 * (sidx) + 0)) << 9) + l * 8;\
    size_t f11 = ((size_t)((((ecw8 + 1) << 5) + 2 * (sidx) + 1)) << 9) + l * 8;\
    Bf[bidx][0] = *(const bf16x8*)(WfH + f00);                                 \
    Bf[bidx][1] = *(const bf16x8*)(WfH + f01);                                 \
    Bf[bidx][2] = *(const bf16x8*)(WfH + f10);                                 \
    Bf[bidx][3] = *(const bf16x8*)(WfH + f11);                                 \
    Bf[bidx][4] = *(const bf16x8*)(WfL + f00);                                 \
    Bf[bidx][5] = *(const bf16x8*)(WfL + f01);                                 \
    Bf[bidx][6] = *(const bf16x8*)(WfL + f10);                                 \
    Bf[bidx][7] = *(const bf16x8*)(WfL + f11);                                 \
  }

    // RQ stage write: hilo(rqv[sidx&1]) -> LDS buf[sidx&1]
#define WQ(sidx) {                                                             \
    const int wb = FRQB((sidx) & 1);                                           \
    _Pragma("unroll")                                                          \
    for (int i = 0; i < 2; i++) {                                              \
      ushort4 h4, l4;                                                          \
      float4 v = rqv[(sidx) & 1][i];                                           \
      hilo(v.x, h4.x, l4.x); hilo(v.y, h4.y, l4.y);                            \
      hilo(v.z, h4.z, l4.z); hilo(v.w, h4.w, l4.w);                            \
      *(ushort4*)(sm + wb + (16 * i + rrow) * 72 + 4 * rcf) = h4;              \
      *(ushort4*)(sm + wb + 2304 + (16 * i + rrow) * 72 + 4 * rcf) = l4;       \
    } }

    // prologue: rq(0), rq(1), B(0), B(1) in flight
#pragma unroll
    for (int i = 0; i < 2; i++)
      rqv[0][i] = *(const float4*)(reprF + baseR + (size_t)(q0 + 16 * i + rrow) * 1024 + 0 + 4 * rcf);
#pragma unroll
    for (int i = 0; i < 2; i++)
      rqv[1][i] = *(const float4*)(reprF + baseR + (size_t)(q0 + 16 * i + rrow) * 1024 + 64 + 4 * rcf);
    LDB(0, 0)
    LDB(1, 1)

    __syncthreads();        // RQ-buf writes vs prev-ec A3 RK reads
    WQ(0)
    __syncthreads();        // write(0) visible

#pragma unroll
    for (int s = 0; s < 16; s++) {
      if (s < 15) WQ(s + 1)                 // buf[(s+1)&1]; data issued earlier
      if (s < 14) {                          // issue rq(s+2) -> rqv[s&1]
        const int d0n = 64 * (s + 2);
#pragma unroll
        for (int i = 0; i < 2; i++)
          rqv[s & 1][i] = *(const float4*)(reprF + baseR + (size_t)(q0 + 16 * i + rrow) * 1024 + d0n + 4 * rcf);
        LDB((s + 2) % 3, s + 2)              // issue B(s+2)
      }
      // compute(s): A from buf[s&1], B from Bf[s%3]
      {
        const int rqb = FRQB(s & 1);
#pragma unroll
        for (int h = 0; h < 2; h++) {
          bf16x8 ah0 = *(const bf16x8*)(sm + rqb + (lr) * 72 + 32 * h + 8 * lg);
          bf16x8 ah1 = *(const bf16x8*)(sm + rqb + (16 + lr) * 72 + 32 * h + 8 * lg);
          bf16x8 al0 = *(const bf16x8*)(sm + rqb + 2304 + (lr) * 72 + 32 * h + 8 * lg);
          bf16x8 al1 = *(const bf16x8*)(sm + rqb + 2304 + (16 + lr) * 72 + 32 * h + 8 * lg);
          bf16x8 bh0 = Bf[s % 3][0 + h];
          bf16x8 bh1 = Bf[s % 3][2 + h];
          bf16x8 bl0 = Bf[s % 3][4 + h];
          bf16x8 bl1 = Bf[s % 3][6 + h];
          acc_q[0][0] = MF(ah0, bh0, acc_q[0][0]);
          acc_q[0][1] = MF(ah0, bh1, acc_q[0][1]);
          acc_q[1][0] = MF(ah1, bh0, acc_q[1][0]);
          acc_q[1][1] = MF(ah1, bh1, acc_q[1][1]);
          acc_q[0][0] = MF(ah0, bl0, acc_q[0][0]);
          acc_q[0][1] = MF(ah0, bl1, acc_q[0][1]);
          acc_q[1][0] = MF(ah1, bl0, acc_q[1][0]);
          acc_q[1][1] = MF(ah1, bl1, acc_q[1][1]);
          acc_q[0][0] = MF(al0, bh0, acc_q[0][0]);
          acc_q[0][1] = MF(al0, bh1, acc_q[0][1]);
          acc_q[1][0] = MF(al1, bh0, acc_q[1][0]);
          acc_q[1][1] = MF(al1, bh1, acc_q[1][1]);
        }
      }
      __syncthreads();     // one barrier per stage
    }
#undef LDB
#undef WQ

    // issue RK loads for es=0 before the A2 VALU pass (latency hides under it)
    float4 rk4[5];
#pragma unroll
    for (int i = 0; i < 5; i++) {
      int slot = i * 256 + tid;
      int row = slot >> 3;
      int kk = q0 - 64 + row;
      kk = kk < 0 ? 0 : (kk > 2047 ? 2047 : kk);
      rk4[i] = *(const float4*)(reprF + baseR + (size_t)kk * 1024 + e0 + 4 * (slot & 7));
    }

    // A2: Q accumulators -> QHI/QLO (hi/lo bf16 split)
#pragma unroll
    for (int qq = 0; qq < 2; qq++)
#pragma unroll
      for (int et = 0; et < 2; et++)
#pragma unroll
        for (int r = 0; r < 4; r++) {
          int row = 16 * qq + 4 * lg + r;
          int col = 32 * w + 16 * et + lr;
          float v = acc_q[qq][et][r];
          unsigned short hi, lo;
          hilo(v, hi, lo);
          sm[FQHI_O + row * 136 + col] = hi;
          sm[FQLO_O + row * 136 + col] = lo;
        }

    // A3: S += Qchunk @ K^T (hi/lo 3-term), 4 e-slices of 32, pipelined
    for (int es = 0; es < 4; es++) {
      __syncthreads();   // RK writes vs d-loop buf reads / prev RK reads; A2 visible
#pragma unroll
      for (int i = 0; i < 5; i++) {
        int slot = i * 256 + tid;
        int row = slot >> 3, cf = slot & 7;
        ushort4 h4, l4;
        hilo(rk4[i].x, h4.x, l4.x); hilo(rk4[i].y, h4.y, l4.y);
        hilo(rk4[i].z, h4.z, l4.z); hilo(rk4[i].w, h4.w, l4.w);
        *(ushort4*)(sm + FRKH_O + row * 40 + 4 * cf) = h4;
        *(ushort4*)(sm + FRKL_O + row * 40 + 4 * cf) = l4;
      }
      __syncthreads();
      if (es < 3) {
#pragma unroll
        for (int i = 0; i < 5; i++) {
          int slot = i * 256 + tid;
          int row = slot >> 3;
          int kk = q0 - 64 + row;
          kk = kk < 0 ? 0 : (kk > 2047 ? 2047 : kk);
          rk4[i] = *(const float4*)(reprF + baseR + (size_t)kk * 1024 + e0 + 32 * (es + 1) + 4 * (slot & 7));
        }
      }
      bf16x8 qh = *(const bf16x8*)(sm + FQHI_O + (16 * qt + lr) * 136 + 32 * es + 8 * lg);
      bf16x8 ql = *(const bf16x8*)(sm + FQLO_O + (16 * qt + lr) * 136 + 32 * es + 8 * lg);
#pragma unroll
      for (int j = 0; j < 5; j++) {
        bf16x8 kh = *(const bf16x8*)(sm + FRKH_O + (16 * (ktb + j) + lr) * 40 + 8 * lg);
        bf16x8 kl = *(const bf16x8*)(sm + FRKL_O + (16 * (ktb + j) + lr) * 40 + 8 * lg);
        acc_s[j] = MF(qh, kh, acc_s[j]);
        acc_s[j] = MF(qh, kl, acc_s[j]);
        acc_s[j] = MF(ql, kh, acc_s[j]);
      }
    }
  }

  __syncthreads();
  // scores -> Sls (f32, pitch 172) @0 (RK/RQ dead)
#pragma unroll
  for (int j = 0; j < 5; j++)
#pragma unroll
    for (int r = 0; r < 4; r++) {
      int row = 16 * qt + 4 * lg + r;
      int col = 16 * (ktb + j) + lr;
      smf[row * 172 + col] = acc_s[j][r];
    }
  __syncthreads();

  // masked softmax (8 lanes/row), probs -> PBF bf16 (@12288, over QHI dead)
  {
    const int row = tid >> 3, l8 = tid & 7;
    int clo = row;          { int t2 = 64 - q0;            if (t2 > clo) clo = t2; }
    int chi = row + 128;    { int t2 = 2047 + 64 - q0;     if (t2 < chi) chi = t2; }
    float m = -1e30f;
    for (int c = l8; c < 160; c += 8)
      if (c >= clo && c <= chi) m = fmaxf(m, smf[row * 172 + c]);
    m = fmaxf(m, __shfl_xor(m, 1));
    m = fmaxf(m, __shfl_xor(m, 2));
    m = fmaxf(m, __shfl_xor(m, 4));
    float ssum = 0.f;
    for (int c = l8; c < 160; c += 8) {
      float e = (c >= clo && c <= chi) ? __expf(smf[row * 172 + c] - m) : 0.f;
      smf[row * 172 + c] = e;
      ssum += e;
    }
    ssum += __shfl_xor(ssum, 1);
    ssum += __shfl_xor(ssum, 2);
    ssum += __shfl_xor(ssum, 4);
    float rinv = 1.f / ssum;
    for (int c = l8; c < 160; c += 8)
      sm[FPBF_O + row * 168 + c] = f2bf(smf[row * 172 + c] * rinv);
  }
  __syncthreads();

  // ---------------- Phase B: ra = P @ V (single-bf16), out = repr+relu -----
  const int dtl = (w & 1) * 2;
  bf16x8 pa[5];
#pragma unroll
  for (int ks = 0; ks < 5; ks++)
    pa[ks] = *(const bf16x8*)(sm + FPBF_O + (16 * qt + lr) * 168 + 32 * ks + 8 * lg);

  float4 vr4[10];
  // prologue: issue dc=0 V loads
#pragma unroll
  for (int i = 0; i < 10; i++) {
    int slot = i * 256 + tid;
    int k = slot >> 4, g = slot & 15;
    int kk = q0 - 64 + k;
    kk = kk < 0 ? 0 : (kk > 2047 ? 2047 : kk);
    vr4[i] = *(const float4*)(reprF + baseR + (size_t)kk * 1024 + 4 * g);
  }

  for (int dc = 0; dc < 16; dc++) {
    const int d0 = dc * 64;
    __syncthreads();   // previous chunk's VT reads done (dc=0: Sls dead)
#pragma unroll
    for (int i = 0; i < 10; i++) {
      int slot = i * 256 + tid;
      int k = slot >> 4, g = slot & 15;
      sm[vtidx(4 * g + 0, k)] = f2bf(vr4[i].x);
      sm[vtidx(4 * g + 1, k)] = f2bf(vr4[i].y);
      sm[vtidx(4 * g + 2, k)] = f2bf(vr4[i].z);
      sm[vtidx(4 * g + 3, k)] = f2bf(vr4[i].w);
    }
    __syncthreads();
    if (dc < 15) {
      const int d0n = d0 + 64;
#pragma unroll
      for (int i = 0; i < 10; i++) {
        int slot = i * 256 + tid;
        int k = slot >> 4, g = slot & 15;
        int kk = q0 - 64 + k;
        kk = kk < 0 ? 0 : (kk > 2047 ? 2047 : kk);
        vr4[i] = *(const float4*)(reprF + baseR + (size_t)kk * 1024 + d0n + 4 * g);
      }
    }
    f32x4 ra0 = (f32x4){0.f, 0.f, 0.f, 0.f};
    f32x4 ra1 = (f32x4){0.f, 0.f, 0.f, 0.f};
    const int row0 = 16 * dtl + lr, row1 = 16 * (dtl + 1) + lr;
#pragma unroll
    for (int ks = 0; ks < 5; ks++) {
      bf16x8 v0 = *(const bf16x8*)(sm + vtidx(row0, 32 * ks + 8 * lg));
      bf16x8 v1 = *(const bf16x8*)(sm + vtidx(row1, 32 * ks + 8 * lg));
      ra0 = MF(pa[ks], v0, ra0);
      ra1 = MF(pa[ks], v1, ra1);
    }
#pragma unroll
    for (int r = 0; r < 4; r++) {
      int qg = q0 + 16 * qt + 4 * lg + r;
      size_t base = baseR + (size_t)qg * 1024 + d0;
      int dg0 = 16 * dtl + lr, dg1 = 16 * (dtl + 1) + lr;
      outF[base + dg0] = reprF[base + dg0] + fmaxf(ra0[r], 0.f);
      outF[base + dg1] = reprF[base + dg1] + fmaxf(ra1[r], 0.f);
    }
  }
}

extern "C" void kernel_launch(void* const* d_in, const int* in_sizes, int n_in,
                              void* d_out, int out_size, void* d_ws, size_t ws_size,
                              hipStream_t stream) {
  const void* repr = d_in[0];
  const void* W    = d_in[1];
  dim3 grid(SEQL / QT, NB);   // (64, 8) = 512 blocks

  const bool use_mfma = (d_ws != nullptr) && (ws_size >= (size_t)4 * 1024 * 1024);
  if (use_mfma) {
    tposeW2<<<dim3(256), dim3(256), 0, stream>>>(repr, W, d_ws);
    attn_mfma<<<grid, dim3(256), 0, stream>>>(
        (const unsigned short*)repr, (const unsigned short*)d_ws, (unsigned short*)d_out);
    attn_mfma_f32<<<grid, dim3(256), 0, stream>>>(
        (const float*)repr, (const unsigned short*)d_ws,
        (const unsigned short*)d_ws + (1u << 20), (float*)d_out);
  } else {
    attn_fused<true><<<grid, dim3(256), 0, stream>>>(repr, W, d_out);
    attn_fused<false><<<grid, dim3(256), 0, stream>>>(repr, W, d_out);
  }
}